// Round 6
// baseline (20554.932 us; speedup 1.0000x reference)
//
#include <hip/hip_runtime.h>
#include <math.h>

#define B_ 16
#define S_ 512
#define FRAME_ 438
#define DM_ 800
#define H_ 8
#define DH_ 100
#define FFN_ 1024
#define HID_ 1024
#define POSE_ 274
#define WIN_ 100
#define G4_ 4096     // 4*HID
#define KPA_ 1536    // padded K for WT_A ([Wh;Wx], K=1298)
#define KPB_ 1024    // K for WT_B (WEFF^T only; enc part precomputed in ENCB)
#define NBLK_SCAN 512
#define WLS_ 1312    // LDS row stride for WT_A slice (>=1298, mult of 4)
#define WLSZ_ (8 * WLS_ + 256)  // + zero tail: last row reads up to WLS_+223 past
#define NSLOT_ 64    // ENCB slots (46 needed at epoch=100)

// h-ring: 513 slots x 16384 floats (64 KB), carved from scan-dead ws regions.
// Slot n holds h after step n-1. Addresses used ONCE: written (sc0/sc1->MALL)
// at step n-1, read (normal cached, L2-absorbed broadcast) at step n.
#define RING_SLOT_F 16384L

// ---------------------------------------------------------------------------
// Coherent (MALL-point) helpers. sc0 sc1 = bypass L1/L2, serve at LLC.
// Rounds 2/3 lesson: NEVER bulk data through these. Used ONLY for h writes
// (2 lines/block/step) and counter polls.
// ---------------------------------------------------------------------------
__device__ __forceinline__ void st_coh(float* p, float v)
{
    asm volatile("global_store_dword %0, %1, off sc0 sc1"
                 :: "v"(p), "v"(v) : "memory");
}

__device__ __forceinline__ unsigned ld_coh_u32(const unsigned* p)
{
    unsigned v;
    asm volatile("global_load_dword %0, %1, off sc0 sc1\n\t"
                 "s_waitcnt vmcnt(0)"
                 : "=v"(v) : "v"(p) : "memory");
    return v;
}

__host__ __device__ __forceinline__ float* ring_slot(float* R, int n)
{
    long off;
    if (n < 248)      off = 30539776L + (long)n * RING_SLOT_F;        // Hall..TAIL gap
    else if (n < 444) off = 4259840L + (long)(n - 248) * RING_SLOT_F; // dead G2 (past BAR)
    else              off = 2244608L + (long)(n - 444) * RING_SLOT_F; // dead WEFF_t tail
    return R + off;
}

// ---------------------------------------------------------------------------
// gemm128: fp32, 128x128 tile, 256 thr, 8x8 micro (split 4+4, conflict-free
// LDS). C = A@B (+bias[N]) (+res[M,N]) (+pos_table[posidx[m]]) (relu).
// ---------------------------------------------------------------------------
__global__ __launch_bounds__(256) void gemm128(
    const float* __restrict__ A, const float* __restrict__ Bm,
    float* __restrict__ C, int M, int N, int K,
    const float* __restrict__ bias, const float* __restrict__ res,
    const int* __restrict__ posidx, const float* __restrict__ postab,
    int relu)
{
    __shared__ float As[16 * 132];
    __shared__ float Bs[16 * 132];
    int m0 = blockIdx.x * 128, n0 = blockIdx.y * 128;
    int tid = threadIdx.x;
    int tx = tid & 15, ty = tid >> 4;
    float acc[8][8];
#pragma unroll
    for (int i = 0; i < 8; ++i)
#pragma unroll
        for (int j = 0; j < 8; ++j) acc[i][j] = 0.f;

    for (int k0 = 0; k0 < K; k0 += 16) {
#pragma unroll
        for (int i = 0; i < 8; ++i) {             // A: 128 m x 16 k
            int idx = i * 256 + tid;
            int m = idx >> 4, kl = idx & 15;
            int r = m0 + m, k = k0 + kl;
            As[kl * 132 + m] = (r < M && k < K) ? A[(long)r * K + k] : 0.f;
        }
#pragma unroll
        for (int i = 0; i < 8; ++i) {             // B: 16 k x 128 n
            int idx = i * 256 + tid;
            int n = idx & 127, k = idx >> 7;
            int kk = k0 + k, nn = n0 + n;
            Bs[k * 132 + n] = (kk < K && nn < N) ? Bm[(long)kk * N + nn] : 0.f;
        }
        __syncthreads();
#pragma unroll
        for (int kk = 0; kk < 16; ++kk) {
            float4 a0 = *(const float4*)&As[kk * 132 + ty * 4];
            float4 a1 = *(const float4*)&As[kk * 132 + 64 + ty * 4];
            float4 b0 = *(const float4*)&Bs[kk * 132 + tx * 4];
            float4 b1 = *(const float4*)&Bs[kk * 132 + 64 + tx * 4];
            float a[8] = {a0.x, a0.y, a0.z, a0.w, a1.x, a1.y, a1.z, a1.w};
            float b[8] = {b0.x, b0.y, b0.z, b0.w, b1.x, b1.y, b1.z, b1.w};
#pragma unroll
            for (int i = 0; i < 8; ++i)
#pragma unroll
                for (int j = 0; j < 8; ++j) acc[i][j] += a[i] * b[j];
        }
        __syncthreads();
    }
#pragma unroll
    for (int i = 0; i < 8; ++i) {
        int m = m0 + ((i < 4) ? (ty * 4 + i) : (64 + ty * 4 + i - 4));
        if (m >= M) continue;
#pragma unroll
        for (int j = 0; j < 8; ++j) {
            int n = n0 + ((j < 4) ? (tx * 4 + j) : (64 + tx * 4 + j - 4));
            if (n >= N) continue;
            float v = acc[i][j];
            if (bias) v += bias[n];
            if (res) v += res[(long)m * N + n];
            if (posidx) v += postab[(long)posidx[m] * N + n];
            if (relu) v = fmaxf(v, 0.f);
            C[(long)m * N + n] = v;
        }
    }
}

// ---------------------------------------------------------------------------
// LayerNorm over last dim N (=800), one block per row.
// ---------------------------------------------------------------------------
__global__ __launch_bounds__(256) void ln_f32(
    const float* __restrict__ X, float* __restrict__ Y,
    const float* __restrict__ g, const float* __restrict__ b, int N)
{
    int m = blockIdx.x;
    const float* x = X + (long)m * N;
    __shared__ float red[256];
    int tid = threadIdx.x;
    float s = 0.f;
    for (int i = tid; i < N; i += 256) s += x[i];
    red[tid] = s; __syncthreads();
    for (int o = 128; o > 0; o >>= 1) { if (tid < o) red[tid] += red[tid + o]; __syncthreads(); }
    float mean = red[0] / N;
    __syncthreads();
    float v = 0.f;
    for (int i = tid; i < N; i += 256) { float d = x[i] - mean; v += d * d; }
    red[tid] = v; __syncthreads();
    for (int o = 128; o > 0; o >>= 1) { if (tid < o) red[tid] += red[tid + o]; __syncthreads(); }
    float rs = rsqrtf(red[0] / N + 1e-6f);
    for (int i = tid; i < N; i += 256)
        Y[(long)m * N + i] = (x[i] - mean) * rs * g[i] + b[i];
}

// ---------------------------------------------------------------------------
// Fused banded attention (verified round 1).
// ---------------------------------------------------------------------------
__global__ __launch_bounds__(256) void attn_f32(
    const float* __restrict__ Q, const float* __restrict__ K,
    const float* __restrict__ V, float* __restrict__ O)
{
    int blk = blockIdx.x;
    int qt = blk & 127; int bh = blk >> 7;
    int h = bh & 7; int b = bh >> 3;
    int q0 = qt * 4;
    int tid = threadIdx.x;

    __shared__ float qv[4][DH_];
    __shared__ float sc[4][208];
    __shared__ float red[256];
    __shared__ float inv_den[4];

    for (int i = tid; i < 4 * DH_; i += 256) {
        int qi = i / DH_, d = i - qi * DH_;
        qv[qi][d] = Q[(long)(b * S_ + q0 + qi) * DM_ + h * DH_ + d];
    }
    __syncthreads();

    int w = tid;
    int k = q0 - WIN_ + w;
    bool kvalid = (w < 204) && (k >= 0) && (k < S_);
    float dots[4] = {0.f, 0.f, 0.f, 0.f};
    if (kvalid) {
        const float* krow = K + (long)(b * S_ + k) * DM_ + h * DH_;
        for (int d = 0; d < DH_; ++d) {
            float kvv = krow[d];
#pragma unroll
            for (int qi = 0; qi < 4; ++qi) dots[qi] += qv[qi][d] * kvv;
        }
    }
#pragma unroll
    for (int qi = 0; qi < 4; ++qi) {
        int wq = w - qi;
        if (w < 204 && wq >= 0 && wq < 201)
            sc[qi][wq] = kvalid ? dots[qi] * 0.1f : -1e30f;
    }
    __syncthreads();

    for (int qi = 0; qi < 4; ++qi) {
        float vmax = (tid < 201) ? sc[qi][tid] : -1e30f;
        red[tid] = vmax; __syncthreads();
        for (int o = 128; o > 0; o >>= 1) { if (tid < o) red[tid] = fmaxf(red[tid], red[tid + o]); __syncthreads(); }
        float mx = red[0];
        __syncthreads();
        float e = 0.f;
        if (tid < 201) { e = __expf(sc[qi][tid] - mx); sc[qi][tid] = e; }
        red[tid] = e; __syncthreads();
        for (int o = 128; o > 0; o >>= 1) { if (tid < o) red[tid] += red[tid + o]; __syncthreads(); }
        if (tid == 0) inv_den[qi] = 1.f / red[0];
        __syncthreads();
    }

    if (tid < DH_) {
        int d = tid;
        float o_[4] = {0.f, 0.f, 0.f, 0.f};
        for (int w2 = 0; w2 < 204; ++w2) {
            int k2 = q0 - WIN_ + w2;
            if (k2 < 0 || k2 >= S_) continue;
            float vv = V[(long)(b * S_ + k2) * DM_ + h * DH_ + d];
#pragma unroll
            for (int qi = 0; qi < 4; ++qi) {
                int wq = w2 - qi;
                if (wq >= 0 && wq < 201) o_[qi] += sc[qi][wq] * vv;
            }
        }
#pragma unroll
        for (int qi = 0; qi < 4; ++qi)
            O[(long)(b * S_ + q0 + qi) * DM_ + h * DH_ + d] = o_[qi] * inv_den[qi];
    }
}

// g3[j] = out_b @ Wx
__global__ __launch_bounds__(256) void g3_kernel(
    const float* __restrict__ outb, const float* __restrict__ Wx, float* __restrict__ g3)
{
    int j = blockIdx.x * 256 + threadIdx.x;
    if (j >= G4_) return;
    float s = 0.f;
    for (int p = 0; p < POSE_; ++p) s += outb[p] * Wx[(long)p * G4_ + j];
    g3[j] = s;
}

// init h state into ring slot 0 (TRANSPOSED: [hid][16]) + zero panel counters
__global__ __launch_bounds__(256) void init_state(
    const float* __restrict__ vh, float* __restrict__ ring0,
    unsigned* __restrict__ bar)
{
    int i = blockIdx.x * 256 + threadIdx.x;
    if (i < B_ * HID_) {
        int bb = i >> 10, hid = i & 1023;
        ring0[hid * 16 + bb] = vh[i];
    }
    if (i < 2080) bar[i] = 0u;
}

// ---------------------------------------------------------------------------
// xb_gather: pack ENC rows needed by B-steps into XB[s*16+b][800].
// B-step s: t = (s/p)*per + (s%p); x row = ENC[b][t-1]. Invalid slots -> 0.
// ---------------------------------------------------------------------------
__global__ __launch_bounds__(256) void xb_gather(
    const float* __restrict__ X, float* __restrict__ XB,
    const int* __restrict__ epoch)
{
    long idx = (long)blockIdx.x * 256 + threadIdx.x;   // < NSLOT_*16*800
    int s = (int)(idx / 12800);
    int rem = (int)(idx - (long)s * 12800);
    int bb = rem / 800, k = rem - bb * 800;
    int p = (int)((double)epoch[0] * 0.01);
    float v = 0.f;
    if (p > 0) {
        int per = p + 10;
        int t = (s / p) * per + (s % p);
        if (t >= 1 && t < S_) v = X[((long)bb * S_ + (t - 1)) * DM_ + k];
    }
    XB[idx] = v;
}

// ---------------------------------------------------------------------------
// tr_cat: WT[c][k] = (k<K1 ? in1[k][c] : k<K1+K2 ? in2[k-K1][c] : 0)
// ---------------------------------------------------------------------------
__global__ __launch_bounds__(256) void tr_cat(
    const float* __restrict__ in1, const float* __restrict__ in2,
    float* __restrict__ WT, int K1, int K2, int KP)
{
    __shared__ float tile[64][65];
    int k0 = blockIdx.x * 64, c0 = blockIdx.y * 64;
    int tid = threadIdx.x;
    int cl = tid & 63, kr = tid >> 6;
#pragma unroll
    for (int i = 0; i < 16; ++i) {
        int kl = i * 4 + kr;
        int k = k0 + kl, c = c0 + cl;
        float v = 0.f;
        if (k < K1) v = in1[(long)k * G4_ + c];
        else if (k < K1 + K2) v = in2[(long)(k - K1) * G4_ + c];
        tile[kl][cl] = v;
    }
    __syncthreads();
    int kl2 = tid & 63, cr = tid >> 6;
#pragma unroll
    for (int i = 0; i < 16; ++i) {
        int ci = i * 4 + cr;
        WT[(long)(c0 + ci) * KP + k0 + kl2] = tile[kl2][ci];
    }
}

// ---------------------------------------------------------------------------
// lstm_scan v5: persistent; weights-in-LDS; fresh-address h ring (proven r5);
// PIPELINED per-panel producer counters instead of a global barrier.
// - h rows [g*256,(g+1)*256) = panel g, produced by blocks 128g..128g+127.
//   Producer: st_coh h -> vmcnt(0) -> relaxed agent RMW on cnt[g_own].
//   Consumer at step t polls cnt[g] >= 128*t just before staging panel g ->
//   a block starts panel-0 compute while panel-3 producers still finish.
//   Monotonic counters + never-reused ring addresses => no reset, no WAR,
//   no deadlock (induction over steps).
// - h panels 1-3 prefetched into regs during compute of the prior panel
//   (poll for g+1 done one panel early); tgt/dec0 rows prefetched at step
//   top (independent of h). Only panel 0's MALL miss stays exposed.
// - pan2 is [b][k] (stride 260): inner loop reads h as ONE ds_read_b128.
//   Same values, same FMA order as the verified kernel.
// - B-steps: K=1024 (h@WEFF^T only, streamed); enc@G2 part precomputed in
//   ENCB (gemm128) and added per gate. ~halves B-step cost + kills the
//   WT_B FETCH stream.
// LDS: WL 43 KB + pan2 16.6 KB = 59.6 KB -> 2 blocks/CU, 512 co-resident.
// ---------------------------------------------------------------------------
__global__ __launch_bounds__(256, 2) void lstm_scan(
    float* __restrict__ Rbase,
    const float* __restrict__ vec_c,
    const float* __restrict__ WT_A, const float* __restrict__ WT_Bh,
    const float* __restrict__ g3, const float* __restrict__ lstm_b,
    const int* __restrict__ epoch,
    const float* __restrict__ tgt, const float* __restrict__ dec0,
    const float* __restrict__ ENCB, float* __restrict__ Hall,
    unsigned* __restrict__ bar)
{
    __shared__ float WL[WLSZ_];        // 8 WT_A rows, stride WLS_
    __shared__ float pan2[16 * 260];   // [b][k] panel; aliases red/gst
    float* red = pan2;
    float* gst = pan2 + 2304;

    int tid = threadIdx.x;
    int hid0 = blockIdx.x * 2;
    int kq = tid >> 4, b = tid & 15;
    int b3 = tid >> 1, hh = tid & 1;
    int p = (int)((double)epoch[0] * 0.01);   // match python int(epoch*LAMB)
    int per = p + 10;
    int g_own = hid0 >> 8;                    // this block's h panel

    // ---- one-time: stage this block's 8 WT_A rows into LDS ----
#pragma unroll
    for (int c = 0; c < 8; ++c) {
        const float* src = WT_A + (long)((c >> 1) * 1024 + hid0 + (c & 1)) * KPA_;
        for (int i = tid * 4; i < WLS_; i += 1024)
            *(float4*)&WL[c * WLS_ + i] = *(const float4*)&src[i];
    }
    for (int i = 8 * WLS_ + tid; i < WLSZ_; i += 256) WL[i] = 0.f;  // NaN guard

    float c_reg = 0.f;
    if (tid < 32) c_reg = vec_c[b3 * HID_ + hid0 + hh];
    __syncthreads();

    for (int t = 0; t < S_; ++t) {
        bool msk = (t % per) >= p;
        bool useA = msk || (t == 0);
        const float* hrd = ring_slot(Rbase, t);
        float*       hwr = ring_slot(Rbase, t + 1);
        unsigned need = (unsigned)t * 128u;

        float acc[8] = {0.f, 0.f, 0.f, 0.f, 0.f, 0.f, 0.f, 0.f};
        float4 v0, v1, v2, v3;

        // helpers (same FMA expression/order as verified kernel)
        auto fmaA = [&](int P) {
#pragma unroll
            for (int j4 = 0; j4 < 4; ++j4) {
                float4 w[8];
#pragma unroll
                for (int c = 0; c < 8; ++c)
                    w[c] = *(const float4*)&WL[c * WLS_ + P + kq * 16 + j4 * 4];
                float4 hv = *(const float4*)&pan2[b * 260 + kq * 16 + j4 * 4];
#pragma unroll
                for (int c = 0; c < 8; ++c)
                    acc[c] += w[c].x * hv.x + w[c].y * hv.y + w[c].z * hv.z + w[c].w * hv.w;
            }
        };
        auto loadh = [&](int P) {
            const float* q = hrd + (long)(P + tid) * 16;
            v0 = *(const float4*)(q);      v1 = *(const float4*)(q + 4);
            v2 = *(const float4*)(q + 8);  v3 = *(const float4*)(q + 12);
        };
        auto writecol = [&]() {
            pan2[0*260+tid]=v0.x;  pan2[1*260+tid]=v0.y;  pan2[2*260+tid]=v0.z;  pan2[3*260+tid]=v0.w;
            pan2[4*260+tid]=v1.x;  pan2[5*260+tid]=v1.y;  pan2[6*260+tid]=v1.z;  pan2[7*260+tid]=v1.w;
            pan2[8*260+tid]=v2.x;  pan2[9*260+tid]=v2.y;  pan2[10*260+tid]=v2.z; pan2[11*260+tid]=v2.w;
            pan2[12*260+tid]=v3.x; pan2[13*260+tid]=v3.y; pan2[14*260+tid]=v3.z; pan2[15*260+tid]=v3.w;
        };
        auto poll = [&](int g) {
            if (tid == 0)
                while (ld_coh_u32(&bar[g * 32]) < need)
                    __builtin_amdgcn_s_sleep(2);
        };

        // tgt/dec0 prefetch (A-steps; independent of h)
        float tp4[16], tp5[16];
        if (useA) {
#pragma unroll
            for (int bb = 0; bb < 16; ++bb) {
                const float* src = msk ? &tgt[((long)bb * S_ + t) * POSE_]
                                       : &dec0[(long)bb * POSE_];
                tp4[bb] = src[tid];                              // tid<256<274
                tp5[bb] = (tid < POSE_ - 256) ? src[256 + tid] : 0.f;
            }
        }

        if (useA) {
            poll(0); __syncthreads();
            loadh(0); writecol(); poll(1); __syncthreads();
            loadh(256);  fmaA(0);    __syncthreads();
            writecol();  poll(2);    __syncthreads();
            loadh(512);  fmaA(256);  __syncthreads();
            writecol();  poll(3);    __syncthreads();
            loadh(768);  fmaA(512);  __syncthreads();
            writecol();  __syncthreads();
            fmaA(768);   __syncthreads();
            // tgt panels
#pragma unroll
            for (int bb = 0; bb < 16; ++bb) pan2[bb * 260 + tid] = tp4[bb];
            __syncthreads();
            fmaA(1024);  __syncthreads();
#pragma unroll
            for (int bb = 0; bb < 16; ++bb) pan2[bb * 260 + tid] = tp5[bb];
            __syncthreads();
            fmaA(1280);  __syncthreads();
        } else {
            const float* wrow[8];
#pragma unroll
            for (int c = 0; c < 8; ++c)
                wrow[c] = WT_Bh + (long)((c >> 1) * 1024 + hid0 + (c & 1)) * KPB_;
            auto fmaB = [&](int P) {
#pragma unroll
                for (int j4 = 0; j4 < 4; ++j4) {
                    float4 w[8];
#pragma unroll
                    for (int c = 0; c < 8; ++c)
                        w[c] = *(const float4*)(wrow[c] + P + kq * 16 + j4 * 4);
                    float4 hv = *(const float4*)&pan2[b * 260 + kq * 16 + j4 * 4];
#pragma unroll
                    for (int c = 0; c < 8; ++c)
                        acc[c] += w[c].x * hv.x + w[c].y * hv.y + w[c].z * hv.z + w[c].w * hv.w;
                }
            };
            poll(0); __syncthreads();
            loadh(0); writecol(); poll(1); __syncthreads();
            loadh(256);  fmaB(0);    __syncthreads();
            writecol();  poll(2);    __syncthreads();
            loadh(512);  fmaB(256);  __syncthreads();
            writecol();  poll(3);    __syncthreads();
            loadh(768);  fmaB(512);  __syncthreads();
            writecol();  __syncthreads();
            fmaB(768);   __syncthreads();
        }

        // ---- reduce 16 k-slices (pan2 dead; red aliases it) ----
#pragma unroll
        for (int c = 0; c < 8; ++c) red[(b * 16 + kq) * 9 + c] = acc[c];
        __syncthreads();

        if (tid < 128) {
            int ob = tid >> 3, oc = tid & 7;
            float s = 0.f;
#pragma unroll
            for (int q = 0; q < 16; ++q) s += red[(ob * 16 + q) * 9 + oc];
            int gcol = (oc >> 1) * 1024 + hid0 + (oc & 1);
            s += lstm_b[gcol];
            if (!useA) {
                int sidx = ((t / per) * p + (t % per)) & (NSLOT_ - 1); // clamp (exact for epoch=100)
                s += g3[gcol] + ENCB[((long)(sidx * 16 + ob)) * G4_ + gcol];
            }
            gst[oc * 16 + ob] = s;
        }
        __syncthreads();

        if (tid < 32) {
            int hid = hid0 + hh;
            float iv = gst[(0 * 2 + hh) * 16 + b3];
            float fv = gst[(1 * 2 + hh) * 16 + b3];
            float gv = gst[(2 * 2 + hh) * 16 + b3];
            float ov = gst[(3 * 2 + hh) * 16 + b3];
            float ig = 1.f / (1.f + __expf(-iv));
            float fg = 1.f / (1.f + __expf(-fv));
            float og = 1.f / (1.f + __expf(-ov));
            float cn = fg * c_reg + ig * tanhf(gv);
            float hn = og * tanhf(cn);
            c_reg = cn;
            st_coh(&hwr[hid * 16 + b3], hn);               // write-through to MALL
            Hall[((long)b3 * S_ + t) * HID_ + hid] = hn;   // normal store
        }
        // arrival: wave 0 only (h stores are wave-0 vmem; vmcnt covers them)
        if (tid == 0) {
            asm volatile("s_waitcnt vmcnt(0)" ::: "memory");
            __hip_atomic_fetch_add(&bar[g_own * 32], 1u,
                                   __ATOMIC_RELAXED, __HIP_MEMORY_SCOPE_AGENT);
        }
        // next iteration's panel-0 poll + syncthreads re-converges the block
    }
}

// ---------------------------------------------------------------------------
extern "C" void kernel_launch(void* const* d_in, const int* in_sizes, int n_in,
                              void* d_out, int out_size, void* d_ws, size_t ws_size,
                              hipStream_t stream) {
    const float* src_seq  = (const float*)d_in[0];
    const int*   src_pos  = (const int*)  d_in[1];
    const float* tgt_seq  = (const float*)d_in[2];
    const float* vec_h    = (const float*)d_in[3];
    const float* vec_c    = (const float*)d_in[4];
    const float* dec0     = (const float*)d_in[5];
    const float* emb_W    = (const float*)d_in[6];
    const float* emb_b    = (const float*)d_in[7];
    const float* pos_tab  = (const float*)d_in[8];
    const float* Wq       = (const float*)d_in[9];
    const float* Wk       = (const float*)d_in[10];
    const float* Wv       = (const float*)d_in[11];
    const float* Wo       = (const float*)d_in[12];
    const float* ln1_g    = (const float*)d_in[13];
    const float* ln1_b    = (const float*)d_in[14];
    const float* ffn_W1   = (const float*)d_in[15];
    const float* ffn_b1   = (const float*)d_in[16];
    const float* ffn_W2   = (const float*)d_in[17];
    const float* ffn_b2   = (const float*)d_in[18];
    const float* ln2_g    = (const float*)d_in[19];
    const float* ln2_b    = (const float*)d_in[20];
    const float* lstm_Wx  = (const float*)d_in[21];
    const float* lstm_Wh  = (const float*)d_in[22];
    const float* lstm_b   = (const float*)d_in[23];
    const float* out_W    = (const float*)d_in[24];
    const float* out_b    = (const float*)d_in[25];
    const int*   epoch    = (const int*)  d_in[26];

    // ---- workspace layout (total 41,209,856 floats = 164.8 MB) ----
    float* ws = (float*)d_ws;
    const long NX = (long)B_ * S_ * DM_;           // 6,553,600
    float* X      = ws;                            // enc / residual [0, NX)
    float* R      = X + NX;                        // 34,603,008-float region
    // encoder phase:
    float* Qb     = R;
    float* Kb     = Qb + NX;
    float* Vb     = Kb + NX;
    float* Ob     = Vb + NX;
    float* FFNH   = Ob + NX;                       // 8,388,608
    // decoder phase (aliases into R; encoder scratch dead):
    float* WEFF_t = R;                             // [0, 4,194,304)
    float* G2m    = R + 4194304;                   // 800x4096 (dead after ENCB gemm)
    float* WT_A   = R + 7471104;                   // 4096 x 1536
    float* WT_B   = R + 13762560;                  // 4096 x 1024 (WEFF^T only)
    float* ENCB   = R + 17956864;                  // 64*16 x 4096 (B-step enc@G2)
    float* Hall   = R + 22151168;                  // B*S x 1024
    float* T1     = WEFF_t;                        // 2,244,608 (after tr_cat B)
    float* XB     = R + 3375104;                   // 64*16 x 800 gather buffer
    float* TAIL   = R + 34603008;
    float* G3v    = TAIL;                          // 4096
    // h-ring (ring_slot): [R+30539776,+248*16K) ; [R+4259840,+196*16K) ;
    //                     [R+2244608,+69*16K). All scan-dead; each addr used once.
    unsigned* BAR = (unsigned*)G2m;                // panel counters (zeroed post-ENCB)

    const int M = B_ * S_; // 8192
    dim3 blk(256);

    // ---- encoder ----
    gemm128<<<dim3(M / 128, (DM_ + 127) / 128), blk, 0, stream>>>(
        src_seq, emb_W, X, M, DM_, FRAME_, emb_b, nullptr, src_pos, pos_tab, 0);
    gemm128<<<dim3(M / 128, (DM_ + 127) / 128), blk, 0, stream>>>(
        X, Wq, Qb, M, DM_, DM_, nullptr, nullptr, nullptr, nullptr, 0);
    gemm128<<<dim3(M / 128, (DM_ + 127) / 128), blk, 0, stream>>>(
        X, Wk, Kb, M, DM_, DM_, nullptr, nullptr, nullptr, nullptr, 0);
    gemm128<<<dim3(M / 128, (DM_ + 127) / 128), blk, 0, stream>>>(
        X, Wv, Vb, M, DM_, DM_, nullptr, nullptr, nullptr, nullptr, 0);
    attn_f32<<<dim3(B_ * H_ * (S_ / 4)), blk, 0, stream>>>(Qb, Kb, Vb, Ob);
    gemm128<<<dim3(M / 128, (DM_ + 127) / 128), blk, 0, stream>>>(
        Ob, Wo, FFNH, M, DM_, DM_, nullptr, X, nullptr, nullptr, 0);
    ln_f32<<<dim3(M), blk, 0, stream>>>(FFNH, X, ln1_g, ln1_b, DM_);
    gemm128<<<dim3(M / 128, FFN_ / 128), blk, 0, stream>>>(
        X, ffn_W1, FFNH, M, FFN_, DM_, ffn_b1, nullptr, nullptr, nullptr, 1);
    gemm128<<<dim3(M / 128, (DM_ + 127) / 128), blk, 0, stream>>>(
        FFNH, ffn_W2, Ob, M, DM_, FFN_, ffn_b2, X, nullptr, nullptr, 0);
    ln_f32<<<dim3(M), blk, 0, stream>>>(Ob, X, ln2_g, ln2_b, DM_);   // X = enc

    // ---- decoder precompute ----
    // WEFF_t = out_W[:1024]@lstm_Wx + lstm_Wh   (1024 x 4096)
    gemm128<<<dim3(HID_ / 128, G4_ / 128), blk, 0, stream>>>(
        out_W, lstm_Wx, WEFF_t, HID_, G4_, POSE_, nullptr, lstm_Wh, nullptr, nullptr, 0);
    // G2m = out_W[1024:]@lstm_Wx   (800 x 4096)
    gemm128<<<dim3((DM_ + 127) / 128, G4_ / 128), blk, 0, stream>>>(
        out_W + (long)HID_ * POSE_, lstm_Wx, G2m, DM_, G4_, POSE_,
        nullptr, nullptr, nullptr, nullptr, 0);
    // transposed, zero-padded step weights
    tr_cat<<<dim3(KPA_ / 64, G4_ / 64), blk, 0, stream>>>(
        lstm_Wh, lstm_Wx, WT_A, HID_, POSE_, KPA_);
    tr_cat<<<dim3(KPB_ / 64, G4_ / 64), blk, 0, stream>>>(
        WEFF_t, WEFF_t, WT_B, HID_, 0, KPB_);      // WEFF^T only
    // gather B-step enc rows (after tr_cat B frees WEFF_t tail where XB lives)
    xb_gather<<<dim3(NSLOT_ * 16 * 800 / 256), blk, 0, stream>>>(X, XB, epoch);
    g3_kernel<<<dim3(G4_ / 256), blk, 0, stream>>>(out_b, lstm_Wx, G3v);
    // ENCB = XB @ G2m  (reads G2m -> must precede init_state's BAR write)
    gemm128<<<dim3(NSLOT_ * 16 / 128, G4_ / 128), blk, 0, stream>>>(
        XB, G2m, ENCB, NSLOT_ * 16, G4_, DM_, nullptr, nullptr, nullptr, nullptr, 0);
    // init h ring slot 0 + zero panel counters (G2m dead now)
    init_state<<<dim3((B_ * HID_ + 255) / 256), blk, 0, stream>>>(
        vec_h, ring_slot(R, 0), BAR);
    // T1 = enc@out_W[1024:,:] + out_b
    gemm128<<<dim3(M / 128, (POSE_ + 127) / 128), blk, 0, stream>>>(
        X, out_W + (long)HID_ * POSE_, T1, M, POSE_, DM_, out_b,
        nullptr, nullptr, nullptr, 0);

    // ---- fused sequential scan: pipelined per-panel producer counters ----
    lstm_scan<<<dim3(NBLK_SCAN), blk, 0, stream>>>(
        R, vec_c, WT_A, WT_B, G3v, lstm_b, epoch,
        tgt_seq, dec0, ENCB, Hall, BAR);

    // ---- final: out = Hall@out_W[:1024] + T1 ----
    gemm128<<<dim3(M / 128, (POSE_ + 127) / 128), blk, 0, stream>>>(
        Hall, out_W, (float*)d_out, M, POSE_, HID_, nullptr, T1,
        nullptr, nullptr, 0);
}

// Round 7
// 18592.122 us; speedup vs baseline: 1.1056x; 1.1056x over previous
//
#include <hip/hip_runtime.h>
#include <math.h>

#define B_ 16
#define S_ 512
#define FRAME_ 438
#define DM_ 800
#define H_ 8
#define DH_ 100
#define FFN_ 1024
#define HID_ 1024
#define POSE_ 274
#define WIN_ 100
#define G4_ 4096     // 4*HID
#define KPA_ 1536    // padded K for WT_A ([Wh;Wx], K=1298)
#define KPB_ 1024    // K for WT_B (WEFF^T only; enc part precomputed in ENCB)
#define NBLK_SCAN 512
#define WLS_ 1312    // LDS row stride for WT_A slice (>=1298, mult of 4)
#define WLSZ_ (8 * WLS_ + 256)  // + zero tail (guards row-7 overrun; pan=0 there)
#define NSLOT_ 64    // ENCB slots (46 needed at epoch=100)

// h-ring: 513 slots x 16384 floats (64 KB), carved from scan-dead ws regions.
// Slot n holds h after step n-1. Addresses used ONCE: written (sc0/sc1->MALL)
// at step n-1, read (normal cached, L2-absorbed broadcast) at step n.
#define RING_SLOT_F 16384L

// ---------------------------------------------------------------------------
// Coherent (MALL-point) helpers. sc0 sc1 = bypass L1/L2, serve at LLC.
// Lessons r2/r3: never bulk data through these. Lesson r6: never POLL a line
// that atomics RMW (dirty-line writeback ping-pong = GBs of HBM traffic).
// Polled lines are written ONLY by st_coh (write-through, clean).
// ---------------------------------------------------------------------------
__device__ __forceinline__ void st_coh(float* p, float v)
{
    asm volatile("global_store_dword %0, %1, off sc0 sc1"
                 :: "v"(p), "v"(v) : "memory");
}

__device__ __forceinline__ void st_coh_u32(unsigned* p, unsigned v)
{
    asm volatile("global_store_dword %0, %1, off sc0 sc1"
                 :: "v"(p), "v"(v) : "memory");
}

__device__ __forceinline__ unsigned ld_coh_u32(const unsigned* p)
{
    unsigned v;
    asm volatile("global_load_dword %0, %1, off sc0 sc1\n\t"
                 "s_waitcnt vmcnt(0)"
                 : "=v"(v) : "v"(p) : "memory");
    return v;
}

__host__ __device__ __forceinline__ float* ring_slot(float* R, int n)
{
    long off;
    if (n < 248)      off = 30539776L + (long)n * RING_SLOT_F;        // Hall..TAIL gap
    else if (n < 444) off = 4259840L + (long)(n - 248) * RING_SLOT_F; // dead G2 (past BAR)
    else              off = 2244608L + (long)(n - 444) * RING_SLOT_F; // dead WEFF_t tail
    return R + off;
}

// ---------------------------------------------------------------------------
// gemm128: fp32, 128x128 tile, 256 thr, 8x8 micro (split 4+4, conflict-free
// LDS). C = A@B (+bias[N]) (+res[M,N]) (+pos_table[posidx[m]]) (relu).
// ---------------------------------------------------------------------------
__global__ __launch_bounds__(256) void gemm128(
    const float* __restrict__ A, const float* __restrict__ Bm,
    float* __restrict__ C, int M, int N, int K,
    const float* __restrict__ bias, const float* __restrict__ res,
    const int* __restrict__ posidx, const float* __restrict__ postab,
    int relu)
{
    __shared__ float As[16 * 132];
    __shared__ float Bs[16 * 132];
    int m0 = blockIdx.x * 128, n0 = blockIdx.y * 128;
    int tid = threadIdx.x;
    int tx = tid & 15, ty = tid >> 4;
    float acc[8][8];
#pragma unroll
    for (int i = 0; i < 8; ++i)
#pragma unroll
        for (int j = 0; j < 8; ++j) acc[i][j] = 0.f;

    for (int k0 = 0; k0 < K; k0 += 16) {
#pragma unroll
        for (int i = 0; i < 8; ++i) {             // A: 128 m x 16 k
            int idx = i * 256 + tid;
            int m = idx >> 4, kl = idx & 15;
            int r = m0 + m, k = k0 + kl;
            As[kl * 132 + m] = (r < M && k < K) ? A[(long)r * K + k] : 0.f;
        }
#pragma unroll
        for (int i = 0; i < 8; ++i) {             // B: 16 k x 128 n
            int idx = i * 256 + tid;
            int n = idx & 127, k = idx >> 7;
            int kk = k0 + k, nn = n0 + n;
            Bs[k * 132 + n] = (kk < K && nn < N) ? Bm[(long)kk * N + nn] : 0.f;
        }
        __syncthreads();
#pragma unroll
        for (int kk = 0; kk < 16; ++kk) {
            float4 a0 = *(const float4*)&As[kk * 132 + ty * 4];
            float4 a1 = *(const float4*)&As[kk * 132 + 64 + ty * 4];
            float4 b0 = *(const float4*)&Bs[kk * 132 + tx * 4];
            float4 b1 = *(const float4*)&Bs[kk * 132 + 64 + tx * 4];
            float a[8] = {a0.x, a0.y, a0.z, a0.w, a1.x, a1.y, a1.z, a1.w};
            float b[8] = {b0.x, b0.y, b0.z, b0.w, b1.x, b1.y, b1.z, b1.w};
#pragma unroll
            for (int i = 0; i < 8; ++i)
#pragma unroll
                for (int j = 0; j < 8; ++j) acc[i][j] += a[i] * b[j];
        }
        __syncthreads();
    }
#pragma unroll
    for (int i = 0; i < 8; ++i) {
        int m = m0 + ((i < 4) ? (ty * 4 + i) : (64 + ty * 4 + i - 4));
        if (m >= M) continue;
#pragma unroll
        for (int j = 0; j < 8; ++j) {
            int n = n0 + ((j < 4) ? (tx * 4 + j) : (64 + tx * 4 + j - 4));
            if (n >= N) continue;
            float v = acc[i][j];
            if (bias) v += bias[n];
            if (res) v += res[(long)m * N + n];
            if (posidx) v += postab[(long)posidx[m] * N + n];
            if (relu) v = fmaxf(v, 0.f);
            C[(long)m * N + n] = v;
        }
    }
}

// ---------------------------------------------------------------------------
// LayerNorm over last dim N (=800), one block per row.
// ---------------------------------------------------------------------------
__global__ __launch_bounds__(256) void ln_f32(
    const float* __restrict__ X, float* __restrict__ Y,
    const float* __restrict__ g, const float* __restrict__ b, int N)
{
    int m = blockIdx.x;
    const float* x = X + (long)m * N;
    __shared__ float red[256];
    int tid = threadIdx.x;
    float s = 0.f;
    for (int i = tid; i < N; i += 256) s += x[i];
    red[tid] = s; __syncthreads();
    for (int o = 128; o > 0; o >>= 1) { if (tid < o) red[tid] += red[tid + o]; __syncthreads(); }
    float mean = red[0] / N;
    __syncthreads();
    float v = 0.f;
    for (int i = tid; i < N; i += 256) { float d = x[i] - mean; v += d * d; }
    red[tid] = v; __syncthreads();
    for (int o = 128; o > 0; o >>= 1) { if (tid < o) red[tid] += red[tid + o]; __syncthreads(); }
    float rs = rsqrtf(red[0] / N + 1e-6f);
    for (int i = tid; i < N; i += 256)
        Y[(long)m * N + i] = (x[i] - mean) * rs * g[i] + b[i];
}

// ---------------------------------------------------------------------------
// Fused banded attention (verified round 1).
// ---------------------------------------------------------------------------
__global__ __launch_bounds__(256) void attn_f32(
    const float* __restrict__ Q, const float* __restrict__ K,
    const float* __restrict__ V, float* __restrict__ O)
{
    int blk = blockIdx.x;
    int qt = blk & 127; int bh = blk >> 7;
    int h = bh & 7; int b = bh >> 3;
    int q0 = qt * 4;
    int tid = threadIdx.x;

    __shared__ float qv[4][DH_];
    __shared__ float sc[4][208];
    __shared__ float red[256];
    __shared__ float inv_den[4];

    for (int i = tid; i < 4 * DH_; i += 256) {
        int qi = i / DH_, d = i - qi * DH_;
        qv[qi][d] = Q[(long)(b * S_ + q0 + qi) * DM_ + h * DH_ + d];
    }
    __syncthreads();

    int w = tid;
    int k = q0 - WIN_ + w;
    bool kvalid = (w < 204) && (k >= 0) && (k < S_);
    float dots[4] = {0.f, 0.f, 0.f, 0.f};
    if (kvalid) {
        const float* krow = K + (long)(b * S_ + k) * DM_ + h * DH_;
        for (int d = 0; d < DH_; ++d) {
            float kvv = krow[d];
#pragma unroll
            for (int qi = 0; qi < 4; ++qi) dots[qi] += qv[qi][d] * kvv;
        }
    }
#pragma unroll
    for (int qi = 0; qi < 4; ++qi) {
        int wq = w - qi;
        if (w < 204 && wq >= 0 && wq < 201)
            sc[qi][wq] = kvalid ? dots[qi] * 0.1f : -1e30f;
    }
    __syncthreads();

    for (int qi = 0; qi < 4; ++qi) {
        float vmax = (tid < 201) ? sc[qi][tid] : -1e30f;
        red[tid] = vmax; __syncthreads();
        for (int o = 128; o > 0; o >>= 1) { if (tid < o) red[tid] = fmaxf(red[tid], red[tid + o]); __syncthreads(); }
        float mx = red[0];
        __syncthreads();
        float e = 0.f;
        if (tid < 201) { e = __expf(sc[qi][tid] - mx); sc[qi][tid] = e; }
        red[tid] = e; __syncthreads();
        for (int o = 128; o > 0; o >>= 1) { if (tid < o) red[tid] += red[tid + o]; __syncthreads(); }
        if (tid == 0) inv_den[qi] = 1.f / red[0];
        __syncthreads();
    }

    if (tid < DH_) {
        int d = tid;
        float o_[4] = {0.f, 0.f, 0.f, 0.f};
        for (int w2 = 0; w2 < 204; ++w2) {
            int k2 = q0 - WIN_ + w2;
            if (k2 < 0 || k2 >= S_) continue;
            float vv = V[(long)(b * S_ + k2) * DM_ + h * DH_ + d];
#pragma unroll
            for (int qi = 0; qi < 4; ++qi) {
                int wq = w2 - qi;
                if (wq >= 0 && wq < 201) o_[qi] += sc[qi][wq] * vv;
            }
        }
#pragma unroll
        for (int qi = 0; qi < 4; ++qi)
            O[(long)(b * S_ + q0 + qi) * DM_ + h * DH_ + d] = o_[qi] * inv_den[qi];
    }
}

// g3[j] = out_b @ Wx
__global__ __launch_bounds__(256) void g3_kernel(
    const float* __restrict__ outb, const float* __restrict__ Wx, float* __restrict__ g3)
{
    int j = blockIdx.x * 256 + threadIdx.x;
    if (j >= G4_) return;
    float s = 0.f;
    for (int p = 0; p < POSE_; ++p) s += outb[p] * Wx[(long)p * G4_ + j];
    g3[j] = s;
}

// init h state into ring slot 0 (TRANSPOSED: [hid][16]) + zero sync state
__global__ __launch_bounds__(256) void init_state(
    const float* __restrict__ vh, float* __restrict__ ring0,
    unsigned* __restrict__ bar)
{
    int i = blockIdx.x * 256 + threadIdx.x;
    if (i < B_ * HID_) {
        int bb = i >> 10, hid = i & 1023;
        ring0[hid * 16 + bb] = vh[i];
    }
    if (i < 4096) bar[i] = 0u;
}

// ---------------------------------------------------------------------------
// xb_gather: pack ENC rows needed by B-steps into XB[s*16+b][800].
// B-step s: t = (s/p)*per + (s%p); x row = ENC[b][t-1]. Invalid slots -> 0.
// ---------------------------------------------------------------------------
__global__ __launch_bounds__(256) void xb_gather(
    const float* __restrict__ X, float* __restrict__ XB,
    const int* __restrict__ epoch)
{
    long idx = (long)blockIdx.x * 256 + threadIdx.x;   // < NSLOT_*16*800
    int s = (int)(idx / 12800);
    int rem = (int)(idx - (long)s * 12800);
    int bb = rem / 800, k = rem - bb * 800;
    int p = (int)((double)epoch[0] * 0.01);
    float v = 0.f;
    if (p > 0) {
        int per = p + 10;
        int t = (s / p) * per + (s % p);
        if (t >= 1 && t < S_) v = X[((long)bb * S_ + (t - 1)) * DM_ + k];
    }
    XB[idx] = v;
}

// ---------------------------------------------------------------------------
// tr_cat: WT[c][k] = (k<K1 ? in1[k][c] : k<K1+K2 ? in2[k-K1][c] : 0)
// ---------------------------------------------------------------------------
__global__ __launch_bounds__(256) void tr_cat(
    const float* __restrict__ in1, const float* __restrict__ in2,
    float* __restrict__ WT, int K1, int K2, int KP)
{
    __shared__ float tile[64][65];
    int k0 = blockIdx.x * 64, c0 = blockIdx.y * 64;
    int tid = threadIdx.x;
    int cl = tid & 63, kr = tid >> 6;
#pragma unroll
    for (int i = 0; i < 16; ++i) {
        int kl = i * 4 + kr;
        int k = k0 + kl, c = c0 + cl;
        float v = 0.f;
        if (k < K1) v = in1[(long)k * G4_ + c];
        else if (k < K1 + K2) v = in2[(long)(k - K1) * G4_ + c];
        tile[kl][cl] = v;
    }
    __syncthreads();
    int kl2 = tid & 63, cr = tid >> 6;
#pragma unroll
    for (int i = 0; i < 16; ++i) {
        int ci = i * 4 + cr;
        WT[(long)(c0 + ci) * KP + k0 + kl2] = tile[kl2][ci];
    }
}

// ---------------------------------------------------------------------------
// Panel sync state (all lines 128 B apart; in dead-G2 region):
//   sub[g][j]   = bar[(g*8+j)*32]    : 16-wide arrival RMW, 16 writers, 0 pollers
//   panel[g]    = bar[(32+g)*32]     : 8-wide RMW (one per subgroup), 0 pollers
//   ready[g][r] = bar[(40+g*8+r)*32] : CLEAN st_coh-written replicas, 16 pollers
// Rule (r6 lesson): RMW lines and polled lines are disjoint.
// ---------------------------------------------------------------------------

// ---------------------------------------------------------------------------
// lstm_scan v6: persistent; weights-in-LDS; fresh-address h ring (proven r5);
// pipelined per-panel consumption with TREE arrival + clean-replica polls.
// pan is the proven [k][b] stride-17 layout (r5: 1.37e8 conflicts).
// B-steps: K=1024 (h@WEFF^T), enc part from precomputed ENCB.
// LDS: WL 43 KB + pan 17.4 KB = 60.4 KB -> 2 blocks/CU, 512 co-resident.
// ---------------------------------------------------------------------------
__global__ __launch_bounds__(256, 2) void lstm_scan(
    float* __restrict__ Rbase,
    const float* __restrict__ vec_c,
    const float* __restrict__ WT_A, const float* __restrict__ WT_Bh,
    const float* __restrict__ g3, const float* __restrict__ lstm_b,
    const int* __restrict__ epoch,
    const float* __restrict__ tgt, const float* __restrict__ dec0,
    const float* __restrict__ ENCB, float* __restrict__ Hall,
    unsigned* __restrict__ bar)
{
    __shared__ float WL[WLSZ_];       // 8 WT_A rows, stride WLS_
    __shared__ float pan[256 * 17];   // [k][b] panel; aliases red/gst
    float* red = pan;
    float* gst = pan + 2304;

    int tid = threadIdx.x;
    int hid0 = blockIdx.x * 2;
    int kq = tid >> 4, b = tid & 15;
    int b3 = tid >> 1, hh = tid & 1;
    int p = (int)((double)epoch[0] * 0.01);   // match python int(epoch*LAMB)
    int per = p + 10;
    int g_own = blockIdx.x >> 7;              // this block's h panel (0..3)
    int sub_j = (blockIdx.x >> 4) & 7;        // subgroup within panel
    int repl  = (blockIdx.x >> 6) & 7;        // which ready replica to poll

    // ---- one-time: stage this block's 8 WT_A rows into LDS ----
#pragma unroll
    for (int c = 0; c < 8; ++c) {
        const float* src = WT_A + (long)((c >> 1) * 1024 + hid0 + (c & 1)) * KPA_;
        for (int i = tid * 4; i < WLS_; i += 1024)
            *(float4*)&WL[c * WLS_ + i] = *(const float4*)&src[i];
    }
    for (int i = 8 * WLS_ + tid; i < WLSZ_; i += 256) WL[i] = 0.f;  // NaN guard

    float c_reg = 0.f;
    if (tid < 32) c_reg = vec_c[b3 * HID_ + hid0 + hh];
    __syncthreads();

    for (int t = 0; t < S_; ++t) {
        bool msk = (t % per) >= p;
        bool useA = msk || (t == 0);
        const float* hrd = ring_slot(Rbase, t);
        float*       hwr = ring_slot(Rbase, t + 1);

        float acc[8] = {0.f, 0.f, 0.f, 0.f, 0.f, 0.f, 0.f, 0.f};
        float4 v0, v1, v2, v3;

        auto loadh = [&](int P) {
            const float* q = hrd + (long)(P + tid) * 16;
            v0 = *(const float4*)(q);      v1 = *(const float4*)(q + 4);
            v2 = *(const float4*)(q + 8);  v3 = *(const float4*)(q + 12);
        };
        auto writecol = [&]() {           // pan[k=tid][b] staging, stride 17
            float* pp = &pan[tid * 17];
            pp[0]=v0.x;  pp[1]=v0.y;  pp[2]=v0.z;  pp[3]=v0.w;
            pp[4]=v1.x;  pp[5]=v1.y;  pp[6]=v1.z;  pp[7]=v1.w;
            pp[8]=v2.x;  pp[9]=v2.y;  pp[10]=v2.z; pp[11]=v2.w;
            pp[12]=v3.x; pp[13]=v3.y; pp[14]=v3.z; pp[15]=v3.w;
        };
        auto fmaA = [&](int P) {
            int kb = P + kq * 16;
#pragma unroll
            for (int j4 = 0; j4 < 4; ++j4) {
                float4 w[8];
#pragma unroll
                for (int c = 0; c < 8; ++c)
                    w[c] = *(const float4*)&WL[c * WLS_ + kb + j4 * 4];
                float h0 = pan[(kq * 16 + j4 * 4 + 0) * 17 + b];
                float h1 = pan[(kq * 16 + j4 * 4 + 1) * 17 + b];
                float h2 = pan[(kq * 16 + j4 * 4 + 2) * 17 + b];
                float h3 = pan[(kq * 16 + j4 * 4 + 3) * 17 + b];
#pragma unroll
                for (int c = 0; c < 8; ++c)
                    acc[c] += w[c].x * h0 + w[c].y * h1 + w[c].z * h2 + w[c].w * h3;
            }
        };
        auto poll = [&](int g) {          // clean-line poll, 16 pollers/line
            if (tid == 0)
                while (ld_coh_u32(&bar[(40 + g * 8 + repl) * 32]) < (unsigned)t)
                    __builtin_amdgcn_s_sleep(8);
        };

        // tgt/dec0 prefetch (A-steps; independent of h)
        float tp4[16], tp5[16];
        if (useA) {
#pragma unroll
            for (int bb = 0; bb < 16; ++bb) {
                const float* src = msk ? &tgt[((long)bb * S_ + t) * POSE_]
                                       : &dec0[(long)bb * POSE_];
                tp4[bb] = src[tid];                              // tid<256<274
                tp5[bb] = (tid < POSE_ - 256) ? src[256 + tid] : 0.f;
            }
        }

        if (useA) {
            poll(0); __syncthreads();
            loadh(0); writecol(); poll(1); __syncthreads();
            loadh(256);  fmaA(0);    __syncthreads();
            writecol();  poll(2);    __syncthreads();
            loadh(512);  fmaA(256);  __syncthreads();
            writecol();  poll(3);    __syncthreads();
            loadh(768);  fmaA(512);  __syncthreads();
            writecol();  __syncthreads();
            fmaA(768);   __syncthreads();
#pragma unroll
            for (int bb = 0; bb < 16; ++bb) pan[tid * 17 + bb] = tp4[bb];
            __syncthreads();
            fmaA(1024);  __syncthreads();
#pragma unroll
            for (int bb = 0; bb < 16; ++bb) pan[tid * 17 + bb] = tp5[bb];
            __syncthreads();
            fmaA(1280);  __syncthreads();
        } else {
            const float* wrow[8];
#pragma unroll
            for (int c = 0; c < 8; ++c)
                wrow[c] = WT_Bh + (long)((c >> 1) * 1024 + hid0 + (c & 1)) * KPB_;
            auto fmaB = [&](int P) {
                int kb = P + kq * 16;
#pragma unroll
                for (int j4 = 0; j4 < 4; ++j4) {
                    float4 w[8];
#pragma unroll
                    for (int c = 0; c < 8; ++c)
                        w[c] = *(const float4*)(wrow[c] + kb + j4 * 4);
                    float h0 = pan[(kq * 16 + j4 * 4 + 0) * 17 + b];
                    float h1 = pan[(kq * 16 + j4 * 4 + 1) * 17 + b];
                    float h2 = pan[(kq * 16 + j4 * 4 + 2) * 17 + b];
                    float h3 = pan[(kq * 16 + j4 * 4 + 3) * 17 + b];
#pragma unroll
                    for (int c = 0; c < 8; ++c)
                        acc[c] += w[c].x * h0 + w[c].y * h1 + w[c].z * h2 + w[c].w * h3;
                }
            };
            poll(0); __syncthreads();
            loadh(0); writecol(); poll(1); __syncthreads();
            loadh(256);  fmaB(0);    __syncthreads();
            writecol();  poll(2);    __syncthreads();
            loadh(512);  fmaB(256);  __syncthreads();
            writecol();  poll(3);    __syncthreads();
            loadh(768);  fmaB(512);  __syncthreads();
            writecol();  __syncthreads();
            fmaB(768);   __syncthreads();
        }

        // ---- reduce 16 k-slices (pan dead; red aliases it) ----
#pragma unroll
        for (int c = 0; c < 8; ++c) red[(b * 16 + kq) * 9 + c] = acc[c];
        __syncthreads();

        if (tid < 128) {
            int ob = tid >> 3, oc = tid & 7;
            float s = 0.f;
#pragma unroll
            for (int q = 0; q < 16; ++q) s += red[(ob * 16 + q) * 9 + oc];
            int gcol = (oc >> 1) * 1024 + hid0 + (oc & 1);
            s += lstm_b[gcol];
            if (!useA) {
                int sidx = ((t / per) * p + (t % per)) & (NSLOT_ - 1);
                s += g3[gcol] + ENCB[((long)(sidx * 16 + ob)) * G4_ + gcol];
            }
            gst[oc * 16 + ob] = s;
        }
        __syncthreads();

        if (tid < 32) {
            int hid = hid0 + hh;
            float iv = gst[(0 * 2 + hh) * 16 + b3];
            float fv = gst[(1 * 2 + hh) * 16 + b3];
            float gv = gst[(2 * 2 + hh) * 16 + b3];
            float ov = gst[(3 * 2 + hh) * 16 + b3];
            float ig = 1.f / (1.f + __expf(-iv));
            float fg = 1.f / (1.f + __expf(-fv));
            float og = 1.f / (1.f + __expf(-ov));
            float cn = fg * c_reg + ig * tanhf(gv);
            float hn = og * tanhf(cn);
            c_reg = cn;
            st_coh(&hwr[hid * 16 + b3], hn);               // write-through to MALL
            Hall[((long)b3 * S_ + t) * HID_ + hid] = hn;   // normal store
        }

        // ---- tree arrival (wave 0; vmcnt covers the st_coh h stores) ----
        if (tid == 0) {
            asm volatile("s_waitcnt vmcnt(0)" ::: "memory");
            unsigned tk = __hip_atomic_fetch_add(&bar[(g_own * 8 + sub_j) * 32], 1u,
                              __ATOMIC_RELAXED, __HIP_MEMORY_SCOPE_AGENT);
            if (tk == (unsigned)(16 * t + 15)) {            // last of 16 in subgroup
                unsigned r = __hip_atomic_fetch_add(&bar[(32 + g_own) * 32], 1u,
                                 __ATOMIC_RELAXED, __HIP_MEMORY_SCOPE_AGENT);
                if (r == (unsigned)(8 * t + 7)) {           // last subgroup of panel
#pragma unroll
                    for (int rr = 0; rr < 8; ++rr)
                        st_coh_u32(&bar[(40 + g_own * 8 + rr) * 32],
                                   (unsigned)(t + 1));
                }
            }
        }
        // next iteration's poll(0)+syncthreads re-converges the block
    }
}

// ---------------------------------------------------------------------------
extern "C" void kernel_launch(void* const* d_in, const int* in_sizes, int n_in,
                              void* d_out, int out_size, void* d_ws, size_t ws_size,
                              hipStream_t stream) {
    const float* src_seq  = (const float*)d_in[0];
    const int*   src_pos  = (const int*)  d_in[1];
    const float* tgt_seq  = (const float*)d_in[2];
    const float* vec_h    = (const float*)d_in[3];
    const float* vec_c    = (const float*)d_in[4];
    const float* dec0     = (const float*)d_in[5];
    const float* emb_W    = (const float*)d_in[6];
    const float* emb_b    = (const float*)d_in[7];
    const float* pos_tab  = (const float*)d_in[8];
    const float* Wq       = (const float*)d_in[9];
    const float* Wk       = (const float*)d_in[10];
    const float* Wv       = (const float*)d_in[11];
    const float* Wo       = (const float*)d_in[12];
    const float* ln1_g    = (const float*)d_in[13];
    const float* ln1_b    = (const float*)d_in[14];
    const float* ffn_W1   = (const float*)d_in[15];
    const float* ffn_b1   = (const float*)d_in[16];
    const float* ffn_W2   = (const float*)d_in[17];
    const float* ffn_b2   = (const float*)d_in[18];
    const float* ln2_g    = (const float*)d_in[19];
    const float* ln2_b    = (const float*)d_in[20];
    const float* lstm_Wx  = (const float*)d_in[21];
    const float* lstm_Wh  = (const float*)d_in[22];
    const float* lstm_b   = (const float*)d_in[23];
    const float* out_W    = (const float*)d_in[24];
    const float* out_b    = (const float*)d_in[25];
    const int*   epoch    = (const int*)  d_in[26];

    // ---- workspace layout (total 41,209,856 floats = 164.8 MB) ----
    float* ws = (float*)d_ws;
    const long NX = (long)B_ * S_ * DM_;           // 6,553,600
    float* X      = ws;                            // enc / residual [0, NX)
    float* R      = X + NX;                        // 34,603,008-float region
    // encoder phase:
    float* Qb     = R;
    float* Kb     = Qb + NX;
    float* Vb     = Kb + NX;
    float* Ob     = Vb + NX;
    float* FFNH   = Ob + NX;                       // 8,388,608
    // decoder phase (aliases into R; encoder scratch dead):
    float* WEFF_t = R;                             // [0, 4,194,304)
    float* G2m    = R + 4194304;                   // 800x4096 (dead after ENCB gemm)
    float* WT_A   = R + 7471104;                   // 4096 x 1536
    float* WT_B   = R + 13762560;                  // 4096 x 1024 (WEFF^T only)
    float* ENCB   = R + 17956864;                  // 64*16 x 4096 (B-step enc@G2)
    float* Hall   = R + 22151168;                  // B*S x 1024
    float* T1     = WEFF_t;                        // 2,244,608 (after tr_cat B)
    float* XB     = R + 3375104;                   // 64*16 x 800 gather buffer
    float* TAIL   = R + 34603008;
    float* G3v    = TAIL;                          // 4096
    // h-ring (ring_slot): [R+30539776,+248*16K) ; [R+4259840,+196*16K) ;
    //                     [R+2244608,+69*16K). All scan-dead; each addr once.
    unsigned* BAR = (unsigned*)G2m;                // sync lines (zeroed post-ENCB)

    const int M = B_ * S_; // 8192
    dim3 blk(256);

    // ---- encoder ----
    gemm128<<<dim3(M / 128, (DM_ + 127) / 128), blk, 0, stream>>>(
        src_seq, emb_W, X, M, DM_, FRAME_, emb_b, nullptr, src_pos, pos_tab, 0);
    gemm128<<<dim3(M / 128, (DM_ + 127) / 128), blk, 0, stream>>>(
        X, Wq, Qb, M, DM_, DM_, nullptr, nullptr, nullptr, nullptr, 0);
    gemm128<<<dim3(M / 128, (DM_ + 127) / 128), blk, 0, stream>>>(
        X, Wk, Kb, M, DM_, DM_, nullptr, nullptr, nullptr, nullptr, 0);
    gemm128<<<dim3(M / 128, (DM_ + 127) / 128), blk, 0, stream>>>(
        X, Wv, Vb, M, DM_, DM_, nullptr, nullptr, nullptr, nullptr, 0);
    attn_f32<<<dim3(B_ * H_ * (S_ / 4)), blk, 0, stream>>>(Qb, Kb, Vb, Ob);
    gemm128<<<dim3(M / 128, (DM_ + 127) / 128), blk, 0, stream>>>(
        Ob, Wo, FFNH, M, DM_, DM_, nullptr, X, nullptr, nullptr, 0);
    ln_f32<<<dim3(M), blk, 0, stream>>>(FFNH, X, ln1_g, ln1_b, DM_);
    gemm128<<<dim3(M / 128, FFN_ / 128), blk, 0, stream>>>(
        X, ffn_W1, FFNH, M, FFN_, DM_, ffn_b1, nullptr, nullptr, nullptr, 1);
    gemm128<<<dim3(M / 128, (DM_ + 127) / 128), blk, 0, stream>>>(
        FFNH, ffn_W2, Ob, M, DM_, FFN_, ffn_b2, X, nullptr, nullptr, 0);
    ln_f32<<<dim3(M), blk, 0, stream>>>(Ob, X, ln2_g, ln2_b, DM_);   // X = enc

    // ---- decoder precompute ----
    gemm128<<<dim3(HID_ / 128, G4_ / 128), blk, 0, stream>>>(
        out_W, lstm_Wx, WEFF_t, HID_, G4_, POSE_, nullptr, lstm_Wh, nullptr, nullptr, 0);
    gemm128<<<dim3((DM_ + 127) / 128, G4_ / 128), blk, 0, stream>>>(
        out_W + (long)HID_ * POSE_, lstm_Wx, G2m, DM_, G4_, POSE_,
        nullptr, nullptr, nullptr, nullptr, 0);
    tr_cat<<<dim3(KPA_ / 64, G4_ / 64), blk, 0, stream>>>(
        lstm_Wh, lstm_Wx, WT_A, HID_, POSE_, KPA_);
    tr_cat<<<dim3(KPB_ / 64, G4_ / 64), blk, 0, stream>>>(
        WEFF_t, WEFF_t, WT_B, HID_, 0, KPB_);      // WEFF^T only
    xb_gather<<<dim3(NSLOT_ * 16 * 800 / 256), blk, 0, stream>>>(X, XB, epoch);
    g3_kernel<<<dim3(G4_ / 256), blk, 0, stream>>>(out_b, lstm_Wx, G3v);
    // ENCB = XB @ G2m  (reads G2m -> must precede init_state's BAR zeroing)
    gemm128<<<dim3(NSLOT_ * 16 / 128, G4_ / 128), blk, 0, stream>>>(
        XB, G2m, ENCB, NSLOT_ * 16, G4_, DM_, nullptr, nullptr, nullptr, nullptr, 0);
    init_state<<<dim3((B_ * HID_ + 255) / 256), blk, 0, stream>>>(
        vec_h, ring_slot(R, 0), BAR);
    gemm128<<<dim3(M / 128, (POSE_ + 127) / 128), blk, 0, stream>>>(
        X, out_W + (long)HID_ * POSE_, T1, M, POSE_, DM_, out_b,
        nullptr, nullptr, nullptr, 0);

    // ---- fused sequential scan ----
    lstm_scan<<<dim3(NBLK_SCAN), blk, 0, stream>>>(
        R, vec_c, WT_A, WT_B, G3v, lstm_b, epoch,
        tgt_seq, dec0, ENCB, Hall, BAR);

    // ---- final: out = Hall@out_W[:1024] + T1 ----
    gemm128<<<dim3(M / 128, (POSE_ + 127) / 128), blk, 0, stream>>>(
        Hall, out_W, (float*)d_out, M, POSE_, HID_, nullptr, T1,
        nullptr, nullptr, 0);
}

// Round 8
// 10636.079 us; speedup vs baseline: 1.9326x; 1.7480x over previous
//
#include <hip/hip_runtime.h>
#include <math.h>

#define B_ 16
#define S_ 512
#define FRAME_ 438
#define DM_ 800
#define H_ 8
#define DH_ 100
#define FFN_ 1024
#define HID_ 1024
#define POSE_ 274
#define WIN_ 100
#define G4_ 4096     // 4*HID
#define KPA_ 1536    // padded K for WT_A ([Wh;Wx], K=1298)
#define KPB_ 1024    // K for WT_B (WEFF^T only; enc part precomputed in ENCB)
#define NBLK_SCAN 512
#define WLS_ 1312    // LDS row stride for WT_A slice (>=1298, mult of 4)
#define WLSZ_ (8 * WLS_ + 256)  // + zero tail (guards row-7 overrun; pan=0 there)
#define NSLOT_ 64    // ENCB slots (46 needed at epoch=100)

// h-ring: 513 slots x 16384 floats (64 KB), carved from scan-dead ws regions.
// Slot n holds h after step n-1. Addresses used ONCE: written (sc0/sc1->MALL)
// at step n-1, read (normal cached, L2-absorbed broadcast) at step n.
#define RING_SLOT_F 16384L

// ---------------------------------------------------------------------------
// Coherent (MALL-point) helpers. sc0 sc1 = bypass L1/L2, serve at LLC.
// Lessons r2/r3: never bulk data through these. Lesson r6/r7: UC-poll spin
// time must be bounded to barrier skew -- ONE poll site per step, after all
// step work; polled lines written ONLY by st_coh (clean), never RMW'd.
// ---------------------------------------------------------------------------
__device__ __forceinline__ void st_coh(float* p, float v)
{
    asm volatile("global_store_dword %0, %1, off sc0 sc1"
                 :: "v"(p), "v"(v) : "memory");
}

__device__ __forceinline__ void st_coh_u32(unsigned* p, unsigned v)
{
    asm volatile("global_store_dword %0, %1, off sc0 sc1"
                 :: "v"(p), "v"(v) : "memory");
}

__device__ __forceinline__ unsigned ld_coh_u32(const unsigned* p)
{
    unsigned v;
    asm volatile("global_load_dword %0, %1, off sc0 sc1\n\t"
                 "s_waitcnt vmcnt(0)"
                 : "=v"(v) : "v"(p) : "memory");
    return v;
}

__host__ __device__ __forceinline__ float* ring_slot(float* R, int n)
{
    long off;
    if (n < 248)      off = 30539776L + (long)n * RING_SLOT_F;        // Hall..TAIL gap
    else if (n < 444) off = 4259840L + (long)(n - 248) * RING_SLOT_F; // dead G2 (past BAR)
    else              off = 2244608L + (long)(n - 444) * RING_SLOT_F; // dead WEFF_t tail
    return R + off;
}

// ---------------------------------------------------------------------------
// gemm128: fp32, 128x128 tile, 256 thr, 8x8 micro (split 4+4, conflict-free
// LDS). C = A@B (+bias[N]) (+res[M,N]) (+pos_table[posidx[m]]) (relu).
// ---------------------------------------------------------------------------
__global__ __launch_bounds__(256) void gemm128(
    const float* __restrict__ A, const float* __restrict__ Bm,
    float* __restrict__ C, int M, int N, int K,
    const float* __restrict__ bias, const float* __restrict__ res,
    const int* __restrict__ posidx, const float* __restrict__ postab,
    int relu)
{
    __shared__ float As[16 * 132];
    __shared__ float Bs[16 * 132];
    int m0 = blockIdx.x * 128, n0 = blockIdx.y * 128;
    int tid = threadIdx.x;
    int tx = tid & 15, ty = tid >> 4;
    float acc[8][8];
#pragma unroll
    for (int i = 0; i < 8; ++i)
#pragma unroll
        for (int j = 0; j < 8; ++j) acc[i][j] = 0.f;

    for (int k0 = 0; k0 < K; k0 += 16) {
#pragma unroll
        for (int i = 0; i < 8; ++i) {             // A: 128 m x 16 k
            int idx = i * 256 + tid;
            int m = idx >> 4, kl = idx & 15;
            int r = m0 + m, k = k0 + kl;
            As[kl * 132 + m] = (r < M && k < K) ? A[(long)r * K + k] : 0.f;
        }
#pragma unroll
        for (int i = 0; i < 8; ++i) {             // B: 16 k x 128 n
            int idx = i * 256 + tid;
            int n = idx & 127, k = idx >> 7;
            int kk = k0 + k, nn = n0 + n;
            Bs[k * 132 + n] = (kk < K && nn < N) ? Bm[(long)kk * N + nn] : 0.f;
        }
        __syncthreads();
#pragma unroll
        for (int kk = 0; kk < 16; ++kk) {
            float4 a0 = *(const float4*)&As[kk * 132 + ty * 4];
            float4 a1 = *(const float4*)&As[kk * 132 + 64 + ty * 4];
            float4 b0 = *(const float4*)&Bs[kk * 132 + tx * 4];
            float4 b1 = *(const float4*)&Bs[kk * 132 + 64 + tx * 4];
            float a[8] = {a0.x, a0.y, a0.z, a0.w, a1.x, a1.y, a1.z, a1.w};
            float b[8] = {b0.x, b0.y, b0.z, b0.w, b1.x, b1.y, b1.z, b1.w};
#pragma unroll
            for (int i = 0; i < 8; ++i)
#pragma unroll
                for (int j = 0; j < 8; ++j) acc[i][j] += a[i] * b[j];
        }
        __syncthreads();
    }
#pragma unroll
    for (int i = 0; i < 8; ++i) {
        int m = m0 + ((i < 4) ? (ty * 4 + i) : (64 + ty * 4 + i - 4));
        if (m >= M) continue;
#pragma unroll
        for (int j = 0; j < 8; ++j) {
            int n = n0 + ((j < 4) ? (tx * 4 + j) : (64 + tx * 4 + j - 4));
            if (n >= N) continue;
            float v = acc[i][j];
            if (bias) v += bias[n];
            if (res) v += res[(long)m * N + n];
            if (posidx) v += postab[(long)posidx[m] * N + n];
            if (relu) v = fmaxf(v, 0.f);
            C[(long)m * N + n] = v;
        }
    }
}

// ---------------------------------------------------------------------------
// LayerNorm over last dim N (=800), one block per row.
// ---------------------------------------------------------------------------
__global__ __launch_bounds__(256) void ln_f32(
    const float* __restrict__ X, float* __restrict__ Y,
    const float* __restrict__ g, const float* __restrict__ b, int N)
{
    int m = blockIdx.x;
    const float* x = X + (long)m * N;
    __shared__ float red[256];
    int tid = threadIdx.x;
    float s = 0.f;
    for (int i = tid; i < N; i += 256) s += x[i];
    red[tid] = s; __syncthreads();
    for (int o = 128; o > 0; o >>= 1) { if (tid < o) red[tid] += red[tid + o]; __syncthreads(); }
    float mean = red[0] / N;
    __syncthreads();
    float v = 0.f;
    for (int i = tid; i < N; i += 256) { float d = x[i] - mean; v += d * d; }
    red[tid] = v; __syncthreads();
    for (int o = 128; o > 0; o >>= 1) { if (tid < o) red[tid] += red[tid + o]; __syncthreads(); }
    float rs = rsqrtf(red[0] / N + 1e-6f);
    for (int i = tid; i < N; i += 256)
        Y[(long)m * N + i] = (x[i] - mean) * rs * g[i] + b[i];
}

// ---------------------------------------------------------------------------
// Fused banded attention (verified round 1).
// ---------------------------------------------------------------------------
__global__ __launch_bounds__(256) void attn_f32(
    const float* __restrict__ Q, const float* __restrict__ K,
    const float* __restrict__ V, float* __restrict__ O)
{
    int blk = blockIdx.x;
    int qt = blk & 127; int bh = blk >> 7;
    int h = bh & 7; int b = bh >> 3;
    int q0 = qt * 4;
    int tid = threadIdx.x;

    __shared__ float qv[4][DH_];
    __shared__ float sc[4][208];
    __shared__ float red[256];
    __shared__ float inv_den[4];

    for (int i = tid; i < 4 * DH_; i += 256) {
        int qi = i / DH_, d = i - qi * DH_;
        qv[qi][d] = Q[(long)(b * S_ + q0 + qi) * DM_ + h * DH_ + d];
    }
    __syncthreads();

    int w = tid;
    int k = q0 - WIN_ + w;
    bool kvalid = (w < 204) && (k >= 0) && (k < S_);
    float dots[4] = {0.f, 0.f, 0.f, 0.f};
    if (kvalid) {
        const float* krow = K + (long)(b * S_ + k) * DM_ + h * DH_;
        for (int d = 0; d < DH_; ++d) {
            float kvv = krow[d];
#pragma unroll
            for (int qi = 0; qi < 4; ++qi) dots[qi] += qv[qi][d] * kvv;
        }
    }
#pragma unroll
    for (int qi = 0; qi < 4; ++qi) {
        int wq = w - qi;
        if (w < 204 && wq >= 0 && wq < 201)
            sc[qi][wq] = kvalid ? dots[qi] * 0.1f : -1e30f;
    }
    __syncthreads();

    for (int qi = 0; qi < 4; ++qi) {
        float vmax = (tid < 201) ? sc[qi][tid] : -1e30f;
        red[tid] = vmax; __syncthreads();
        for (int o = 128; o > 0; o >>= 1) { if (tid < o) red[tid] = fmaxf(red[tid], red[tid + o]); __syncthreads(); }
        float mx = red[0];
        __syncthreads();
        float e = 0.f;
        if (tid < 201) { e = __expf(sc[qi][tid] - mx); sc[qi][tid] = e; }
        red[tid] = e; __syncthreads();
        for (int o = 128; o > 0; o >>= 1) { if (tid < o) red[tid] += red[tid + o]; __syncthreads(); }
        if (tid == 0) inv_den[qi] = 1.f / red[0];
        __syncthreads();
    }

    if (tid < DH_) {
        int d = tid;
        float o_[4] = {0.f, 0.f, 0.f, 0.f};
        for (int w2 = 0; w2 < 204; ++w2) {
            int k2 = q0 - WIN_ + w2;
            if (k2 < 0 || k2 >= S_) continue;
            float vv = V[(long)(b * S_ + k2) * DM_ + h * DH_ + d];
#pragma unroll
            for (int qi = 0; qi < 4; ++qi) {
                int wq = w2 - qi;
                if (wq >= 0 && wq < 201) o_[qi] += sc[qi][wq] * vv;
            }
        }
#pragma unroll
        for (int qi = 0; qi < 4; ++qi)
            O[(long)(b * S_ + q0 + qi) * DM_ + h * DH_ + d] = o_[qi] * inv_den[qi];
    }
}

// g3[j] = out_b @ Wx
__global__ __launch_bounds__(256) void g3_kernel(
    const float* __restrict__ outb, const float* __restrict__ Wx, float* __restrict__ g3)
{
    int j = blockIdx.x * 256 + threadIdx.x;
    if (j >= G4_) return;
    float s = 0.f;
    for (int p = 0; p < POSE_; ++p) s += outb[p] * Wx[(long)p * G4_ + j];
    g3[j] = s;
}

// init h state into ring slot 0 (TRANSPOSED: [hid][16]) + zero sync state
__global__ __launch_bounds__(256) void init_state(
    const float* __restrict__ vh, float* __restrict__ ring0,
    unsigned* __restrict__ bar)
{
    int i = blockIdx.x * 256 + threadIdx.x;
    if (i < B_ * HID_) {
        int bb = i >> 10, hid = i & 1023;
        ring0[hid * 16 + bb] = vh[i];
    }
    if (i < 4096) bar[i] = 0u;
}

// ---------------------------------------------------------------------------
// xb_gather: pack ENC rows needed by B-steps into XB[s*16+b][800].
// ---------------------------------------------------------------------------
__global__ __launch_bounds__(256) void xb_gather(
    const float* __restrict__ X, float* __restrict__ XB,
    const int* __restrict__ epoch)
{
    long idx = (long)blockIdx.x * 256 + threadIdx.x;   // < NSLOT_*16*800
    int s = (int)(idx / 12800);
    int rem = (int)(idx - (long)s * 12800);
    int bb = rem / 800, k = rem - bb * 800;
    int p = (int)((double)epoch[0] * 0.01);
    float v = 0.f;
    if (p > 0) {
        int per = p + 10;
        int t = (s / p) * per + (s % p);
        if (t >= 1 && t < S_) v = X[((long)bb * S_ + (t - 1)) * DM_ + k];
    }
    XB[idx] = v;
}

// ---------------------------------------------------------------------------
// tr_cat: WT[c][k] = (k<K1 ? in1[k][c] : k<K1+K2 ? in2[k-K1][c] : 0)
// ---------------------------------------------------------------------------
__global__ __launch_bounds__(256) void tr_cat(
    const float* __restrict__ in1, const float* __restrict__ in2,
    float* __restrict__ WT, int K1, int K2, int KP)
{
    __shared__ float tile[64][65];
    int k0 = blockIdx.x * 64, c0 = blockIdx.y * 64;
    int tid = threadIdx.x;
    int cl = tid & 63, kr = tid >> 6;
#pragma unroll
    for (int i = 0; i < 16; ++i) {
        int kl = i * 4 + kr;
        int k = k0 + kl, c = c0 + cl;
        float v = 0.f;
        if (k < K1) v = in1[(long)k * G4_ + c];
        else if (k < K1 + K2) v = in2[(long)(k - K1) * G4_ + c];
        tile[kl][cl] = v;
    }
    __syncthreads();
    int kl2 = tid & 63, cr = tid >> 6;
#pragma unroll
    for (int i = 0; i < 16; ++i) {
        int ci = i * 4 + cr;
        WT[(long)(c0 + ci) * KP + k0 + kl2] = tile[kl2][ci];
    }
}

// ---------------------------------------------------------------------------
// lstm_scan v7: r5's PROVEN sync (two-level arrival, 32 clean gen replicas,
// ONE poll/step) restructured as a SPLIT barrier:
//   arrive at end of step t  ->  wait at first h-use in step t+1.
// Between them, h-independent work overlaps the barrier skew:
//   - tgt/dec0 register prefetch issued at step top (loads in flight during
//     the poll),
//   - the two tgt FMA phases (k=1024..1535) computed into acc2 BEFORE the
//     wait (~1/3 of A-step VALU work),
//   - all 4 h-panels issued as ONE load batch after the wait (single exposed
//     MALL round trip instead of a serialized chain).
// Numerics: per-thread sum is (h-part)+(tgt-part) -- 1-ulp re-association of
// the class already validated by the ENCB change. Everything else identical.
// B-steps: K=1024 h@WEFF^T + precomputed ENCB (r7-verified).
// LDS: WL 43 KB + pan 17.4 KB = 60.4 KB -> 2 blocks/CU, 512 co-resident.
// ---------------------------------------------------------------------------
__global__ __launch_bounds__(256, 2) void lstm_scan(
    float* __restrict__ Rbase,
    const float* __restrict__ vec_c,
    const float* __restrict__ WT_A, const float* __restrict__ WT_Bh,
    const float* __restrict__ g3, const float* __restrict__ lstm_b,
    const int* __restrict__ epoch,
    const float* __restrict__ tgt, const float* __restrict__ dec0,
    const float* __restrict__ ENCB, float* __restrict__ Hall,
    unsigned* __restrict__ bar)
{
    __shared__ float WL[WLSZ_];       // 8 WT_A rows, stride WLS_
    __shared__ float pan[256 * 17];   // [k][b] panel; aliases red/gst
    float* red = pan;
    float* gst = pan + 2304;

    int tid = threadIdx.x;
    int hid0 = blockIdx.x * 2;
    int kq = tid >> 4, b = tid & 15;
    int b3 = tid >> 1, hh = tid & 1;
    int p = (int)((double)epoch[0] * 0.01);   // match python int(epoch*LAMB)
    int per = p + 10;
    unsigned grp = (unsigned)blockIdx.x >> 4;  // 32 groups x 16 blocks
    unsigned* gcnt = bar;                      // 32 RMW lines (never polled)
    unsigned* root = bar + 1024;               // 1 RMW line  (never polled)
    unsigned* genA = bar + 1056;               // 32 clean replicas (st_coh only)

    // ---- one-time: stage this block's 8 WT_A rows into LDS ----
#pragma unroll
    for (int c = 0; c < 8; ++c) {
        const float* src = WT_A + (long)((c >> 1) * 1024 + hid0 + (c & 1)) * KPA_;
        for (int i = tid * 4; i < WLS_; i += 1024)
            *(float4*)&WL[c * WLS_ + i] = *(const float4*)&src[i];
    }
    for (int i = 8 * WLS_ + tid; i < WLSZ_; i += 256) WL[i] = 0.f;  // NaN guard

    float c_reg = 0.f;
    if (tid < 32) c_reg = vec_c[b3 * HID_ + hid0 + hh];
    __syncthreads();

    for (int t = 0; t < S_; ++t) {
        bool msk = (t % per) >= p;
        bool useA = msk || (t == 0);
        const float* hrd = ring_slot(Rbase, t);
        float*       hwr = ring_slot(Rbase, t + 1);

        float acc[8]  = {0.f, 0.f, 0.f, 0.f, 0.f, 0.f, 0.f, 0.f};
        float acc2[8] = {0.f, 0.f, 0.f, 0.f, 0.f, 0.f, 0.f, 0.f};

        auto fma_wl = [&](int P, float* a) {
            int kb = P + kq * 16;
#pragma unroll
            for (int j4 = 0; j4 < 4; ++j4) {
                float4 w[8];
#pragma unroll
                for (int c = 0; c < 8; ++c)
                    w[c] = *(const float4*)&WL[c * WLS_ + kb + j4 * 4];
                float h0 = pan[(kq * 16 + j4 * 4 + 0) * 17 + b];
                float h1 = pan[(kq * 16 + j4 * 4 + 1) * 17 + b];
                float h2 = pan[(kq * 16 + j4 * 4 + 2) * 17 + b];
                float h3 = pan[(kq * 16 + j4 * 4 + 3) * 17 + b];
#pragma unroll
                for (int c = 0; c < 8; ++c)
                    a[c] += w[c].x * h0 + w[c].y * h1 + w[c].z * h2 + w[c].w * h3;
            }
        };
        auto loadh4 = [&](float4 v[4], int P) {
            const float* q = hrd + (long)(P + tid) * 16;
            v[0] = *(const float4*)(q);      v[1] = *(const float4*)(q + 4);
            v[2] = *(const float4*)(q + 8);  v[3] = *(const float4*)(q + 12);
        };
        auto writecol = [&](const float4 v[4]) {   // pan[k=tid][b], stride 17
            float* pp = &pan[tid * 17];
            pp[0]=v[0].x;  pp[1]=v[0].y;  pp[2]=v[0].z;  pp[3]=v[0].w;
            pp[4]=v[1].x;  pp[5]=v[1].y;  pp[6]=v[1].z;  pp[7]=v[1].w;
            pp[8]=v[2].x;  pp[9]=v[2].y;  pp[10]=v[2].z; pp[11]=v[2].w;
            pp[12]=v[3].x; pp[13]=v[3].y; pp[14]=v[3].z; pp[15]=v[3].w;
        };

        // ---- 1. issue tgt/dec0 prefetch (independent of h; in flight
        //         through the poll below) ----
        float tp4[16], tp5[16];
        if (useA) {
#pragma unroll
            for (int bb = 0; bb < 16; ++bb) {
                const float* src = msk ? &tgt[((long)bb * S_ + t) * POSE_]
                                       : &dec0[(long)bb * POSE_];
                tp4[bb] = src[tid];                              // tid<256<274
                tp5[bb] = (tid < POSE_ - 256) ? src[256 + tid] : 0.f;
            }
        }

        if (useA) {
            // ---- 2. tgt FMA phases into acc2 (no h dependence) ----
#pragma unroll
            for (int bb = 0; bb < 16; ++bb) pan[tid * 17 + bb] = tp4[bb];
            __syncthreads();
            fma_wl(1024, acc2);  __syncthreads();
#pragma unroll
            for (int bb = 0; bb < 16; ++bb) pan[tid * 17 + bb] = tp5[bb];
            __syncthreads();
            fma_wl(1280, acc2);  __syncthreads();
        }

        // ---- 3. WAIT for h_t (one poll site/step; clean replica line) ----
        if (t > 0) {
            if (tid == 0)
                while (ld_coh_u32(&genA[grp * 32]) < (unsigned)t)
                    __builtin_amdgcn_s_sleep(8);
            __syncthreads();
        }

        // ---- 4. h phases: all 4 panels issued as one batch ----
        float4 hA[4], hB[4], hC[4], hD[4];
        loadh4(hA, 0); loadh4(hB, 256); loadh4(hC, 512); loadh4(hD, 768);
        if (useA) {
            writecol(hA); __syncthreads(); fma_wl(0, acc);   __syncthreads();
            writecol(hB); __syncthreads(); fma_wl(256, acc); __syncthreads();
            writecol(hC); __syncthreads(); fma_wl(512, acc); __syncthreads();
            writecol(hD); __syncthreads(); fma_wl(768, acc); __syncthreads();
        } else {
            const float* wrow[8];
#pragma unroll
            for (int c = 0; c < 8; ++c)
                wrow[c] = WT_Bh + (long)((c >> 1) * 1024 + hid0 + (c & 1)) * KPB_;
            auto fmaB = [&](int P) {
                int kb = P + kq * 16;
#pragma unroll
                for (int j4 = 0; j4 < 4; ++j4) {
                    float4 w[8];
#pragma unroll
                    for (int c = 0; c < 8; ++c)
                        w[c] = *(const float4*)(wrow[c] + kb + j4 * 4);
                    float h0 = pan[(kq * 16 + j4 * 4 + 0) * 17 + b];
                    float h1 = pan[(kq * 16 + j4 * 4 + 1) * 17 + b];
                    float h2 = pan[(kq * 16 + j4 * 4 + 2) * 17 + b];
                    float h3 = pan[(kq * 16 + j4 * 4 + 3) * 17 + b];
#pragma unroll
                    for (int c = 0; c < 8; ++c)
                        acc[c] += w[c].x * h0 + w[c].y * h1 + w[c].z * h2 + w[c].w * h3;
                }
            };
            writecol(hA); __syncthreads(); fmaB(0);   __syncthreads();
            writecol(hB); __syncthreads(); fmaB(256); __syncthreads();
            writecol(hC); __syncthreads(); fmaB(512); __syncthreads();
            writecol(hD); __syncthreads(); fmaB(768); __syncthreads();
        }

        // ---- 5. reduce 16 k-slices (pan dead; red aliases it) ----
#pragma unroll
        for (int c = 0; c < 8; ++c) red[(b * 16 + kq) * 9 + c] = acc[c] + acc2[c];
        __syncthreads();

        if (tid < 128) {
            int ob = tid >> 3, oc = tid & 7;
            float s = 0.f;
#pragma unroll
            for (int q = 0; q < 16; ++q) s += red[(ob * 16 + q) * 9 + oc];
            int gcol = (oc >> 1) * 1024 + hid0 + (oc & 1);
            s += lstm_b[gcol];
            if (!useA) {
                int sidx = ((t / per) * p + (t % per)) & (NSLOT_ - 1);
                s += g3[gcol] + ENCB[((long)(sidx * 16 + ob)) * G4_ + gcol];
            }
            gst[oc * 16 + ob] = s;
        }
        __syncthreads();

        if (tid < 32) {
            int hid = hid0 + hh;
            float iv = gst[(0 * 2 + hh) * 16 + b3];
            float fv = gst[(1 * 2 + hh) * 16 + b3];
            float gv = gst[(2 * 2 + hh) * 16 + b3];
            float ov = gst[(3 * 2 + hh) * 16 + b3];
            float ig = 1.f / (1.f + __expf(-iv));
            float fg = 1.f / (1.f + __expf(-fv));
            float og = 1.f / (1.f + __expf(-ov));
            float cn = fg * c_reg + ig * tanhf(gv);
            float hn = og * tanhf(cn);
            c_reg = cn;
            st_coh(&hwr[hid * 16 + b3], hn);               // write-through to MALL
            Hall[((long)b3 * S_ + t) * HID_ + hid] = hn;   // normal store
        }

        // ---- 6. ARRIVE (r5-proven chain; wave 0, vmcnt covers h stores) ----
        if (tid == 0) {
            asm volatile("s_waitcnt vmcnt(0)" ::: "memory");
            unsigned tk = __hip_atomic_fetch_add(&gcnt[grp * 32], 1u,
                              __ATOMIC_RELAXED, __HIP_MEMORY_SCOPE_AGENT);
            if (tk == (unsigned)(16 * t + 15)) {            // last in group
                unsigned r = __hip_atomic_fetch_add(root, 1u,
                                 __ATOMIC_RELAXED, __HIP_MEMORY_SCOPE_AGENT);
                if (r == (unsigned)(32 * t + 31)) {         // last group
#pragma unroll
                    for (int j = 0; j < 32; ++j)
                        st_coh_u32(&genA[j * 32], (unsigned)(t + 1));
                }
            }
        }
        __syncthreads();   // protects pan (gst) from next step's tgt staging
    }
}

// ---------------------------------------------------------------------------
extern "C" void kernel_launch(void* const* d_in, const int* in_sizes, int n_in,
                              void* d_out, int out_size, void* d_ws, size_t ws_size,
                              hipStream_t stream) {
    const float* src_seq  = (const float*)d_in[0];
    const int*   src_pos  = (const int*)  d_in[1];
    const float* tgt_seq  = (const float*)d_in[2];
    const float* vec_h    = (const float*)d_in[3];
    const float* vec_c    = (const float*)d_in[4];
    const float* dec0     = (const float*)d_in[5];
    const float* emb_W    = (const float*)d_in[6];
    const float* emb_b    = (const float*)d_in[7];
    const float* pos_tab  = (const float*)d_in[8];
    const float* Wq       = (const float*)d_in[9];
    const float* Wk       = (const float*)d_in[10];
    const float* Wv       = (const float*)d_in[11];
    const float* Wo       = (const float*)d_in[12];
    const float* ln1_g    = (const float*)d_in[13];
    const float* ln1_b    = (const float*)d_in[14];
    const float* ffn_W1   = (const float*)d_in[15];
    const float* ffn_b1   = (const float*)d_in[16];
    const float* ffn_W2   = (const float*)d_in[17];
    const float* ffn_b2   = (const float*)d_in[18];
    const float* ln2_g    = (const float*)d_in[19];
    const float* ln2_b    = (const float*)d_in[20];
    const float* lstm_Wx  = (const float*)d_in[21];
    const float* lstm_Wh  = (const float*)d_in[22];
    const float* lstm_b   = (const float*)d_in[23];
    const float* out_W    = (const float*)d_in[24];
    const float* out_b    = (const float*)d_in[25];
    const int*   epoch    = (const int*)  d_in[26];

    // ---- workspace layout (total 41,209,856 floats = 164.8 MB) ----
    float* ws = (float*)d_ws;
    const long NX = (long)B_ * S_ * DM_;           // 6,553,600
    float* X      = ws;                            // enc / residual [0, NX)
    float* R      = X + NX;                        // 34,603,008-float region
    // encoder phase:
    float* Qb     = R;
    float* Kb     = Qb + NX;
    float* Vb     = Kb + NX;
    float* Ob     = Vb + NX;
    float* FFNH   = Ob + NX;                       // 8,388,608
    // decoder phase (aliases into R; encoder scratch dead):
    float* WEFF_t = R;                             // [0, 4,194,304)
    float* G2m    = R + 4194304;                   // 800x4096 (dead after ENCB gemm)
    float* WT_A   = R + 7471104;                   // 4096 x 1536
    float* WT_B   = R + 13762560;                  // 4096 x 1024 (WEFF^T only)
    float* ENCB   = R + 17956864;                  // 64*16 x 4096 (B-step enc@G2)
    float* Hall   = R + 22151168;                  // B*S x 1024
    float* T1     = WEFF_t;                        // 2,244,608 (after tr_cat B)
    float* XB     = R + 3375104;                   // 64*16 x 800 gather buffer
    float* TAIL   = R + 34603008;
    float* G3v    = TAIL;                          // 4096
    // h-ring (ring_slot): [R+30539776,+248*16K) ; [R+4259840,+196*16K) ;
    //                     [R+2244608,+69*16K). All scan-dead; each addr once.
    unsigned* BAR = (unsigned*)G2m;                // sync lines (zeroed post-ENCB)

    const int M = B_ * S_; // 8192
    dim3 blk(256);

    // ---- encoder ----
    gemm128<<<dim3(M / 128, (DM_ + 127) / 128), blk, 0, stream>>>(
        src_seq, emb_W, X, M, DM_, FRAME_, emb_b, nullptr, src_pos, pos_tab, 0);
    gemm128<<<dim3(M / 128, (DM_ + 127) / 128), blk, 0, stream>>>(
        X, Wq, Qb, M, DM_, DM_, nullptr, nullptr, nullptr, nullptr, 0);
    gemm128<<<dim3(M / 128, (DM_ + 127) / 128), blk, 0, stream>>>(
        X, Wk, Kb, M, DM_, DM_, nullptr, nullptr, nullptr, nullptr, 0);
    gemm128<<<dim3(M / 128, (DM_ + 127) / 128), blk, 0, stream>>>(
        X, Wv, Vb, M, DM_, DM_, nullptr, nullptr, nullptr, nullptr, 0);
    attn_f32<<<dim3(B_ * H_ * (S_ / 4)), blk, 0, stream>>>(Qb, Kb, Vb, Ob);
    gemm128<<<dim3(M / 128, (DM_ + 127) / 128), blk, 0, stream>>>(
        Ob, Wo, FFNH, M, DM_, DM_, nullptr, X, nullptr, nullptr, 0);
    ln_f32<<<dim3(M), blk, 0, stream>>>(FFNH, X, ln1_g, ln1_b, DM_);
    gemm128<<<dim3(M / 128, FFN_ / 128), blk, 0, stream>>>(
        X, ffn_W1, FFNH, M, FFN_, DM_, ffn_b1, nullptr, nullptr, nullptr, 1);
    gemm128<<<dim3(M / 128, (DM_ + 127) / 128), blk, 0, stream>>>(
        FFNH, ffn_W2, Ob, M, DM_, FFN_, ffn_b2, X, nullptr, nullptr, 0);
    ln_f32<<<dim3(M), blk, 0, stream>>>(Ob, X, ln2_g, ln2_b, DM_);   // X = enc

    // ---- decoder precompute ----
    gemm128<<<dim3(HID_ / 128, G4_ / 128), blk, 0, stream>>>(
        out_W, lstm_Wx, WEFF_t, HID_, G4_, POSE_, nullptr, lstm_Wh, nullptr, nullptr, 0);
    gemm128<<<dim3((DM_ + 127) / 128, G4_ / 128), blk, 0, stream>>>(
        out_W + (long)HID_ * POSE_, lstm_Wx, G2m, DM_, G4_, POSE_,
        nullptr, nullptr, nullptr, nullptr, 0);
    tr_cat<<<dim3(KPA_ / 64, G4_ / 64), blk, 0, stream>>>(
        lstm_Wh, lstm_Wx, WT_A, HID_, POSE_, KPA_);
    tr_cat<<<dim3(KPB_ / 64, G4_ / 64), blk, 0, stream>>>(
        WEFF_t, WEFF_t, WT_B, HID_, 0, KPB_);      // WEFF^T only
    xb_gather<<<dim3(NSLOT_ * 16 * 800 / 256), blk, 0, stream>>>(X, XB, epoch);
    g3_kernel<<<dim3(G4_ / 256), blk, 0, stream>>>(out_b, lstm_Wx, G3v);
    // ENCB = XB @ G2m  (reads G2m -> must precede init_state's BAR zeroing)
    gemm128<<<dim3(NSLOT_ * 16 / 128, G4_ / 128), blk, 0, stream>>>(
        XB, G2m, ENCB, NSLOT_ * 16, G4_, DM_, nullptr, nullptr, nullptr, nullptr, 0);
    init_state<<<dim3((B_ * HID_ + 255) / 256), blk, 0, stream>>>(
        vec_h, ring_slot(R, 0), BAR);
    gemm128<<<dim3(M / 128, (POSE_ + 127) / 128), blk, 0, stream>>>(
        X, out_W + (long)HID_ * POSE_, T1, M, POSE_, DM_, out_b,
        nullptr, nullptr, nullptr, 0);

    // ---- fused sequential scan: split barrier, r5-proven sync chain ----
    lstm_scan<<<dim3(NBLK_SCAN), blk, 0, stream>>>(
        R, vec_c, WT_A, WT_B, G3v, lstm_b, epoch,
        tgt_seq, dec0, ENCB, Hall, BAR);

    // ---- final: out = Hall@out_W[:1024] + T1 ----
    gemm128<<<dim3(M / 128, (POSE_ + 127) / 128), blk, 0, stream>>>(
        Hall, out_W, (float*)d_out, M, POSE_, HID_, nullptr, T1,
        nullptr, nullptr, 0);
}

// Round 9
// 9582.264 us; speedup vs baseline: 2.1451x; 1.1100x over previous
//
#include <hip/hip_runtime.h>
#include <math.h>

#define B_ 16
#define S_ 512
#define FRAME_ 438
#define DM_ 800
#define H_ 8
#define DH_ 100
#define FFN_ 1024
#define HID_ 1024
#define POSE_ 274
#define WIN_ 100
#define G4_ 4096     // 4*HID
#define KPA_ 1536    // padded K for WT_A ([Wh;Wx], K=1298)
#define KPB_ 1024    // K for WT_B (WEFF^T only; enc part precomputed in ENCB)
#define NBLK_SCAN 512
#define WLS_ 1312    // LDS row stride for WT_A slice (>=1298, mult of 4)
#define WLSZ_ (8 * WLS_ + 256)  // + zero tail (guards row-7 overrun; pan=0 there)
#define NSLOT_ 64    // ENCB slots (46 needed at epoch=100)

// h-ring: 513 slots x 16384 floats (64 KB), carved from scan-dead ws regions.
// Slot n holds h after step n-1. Addresses used ONCE: written (sc0/sc1->MALL)
// at step n-1, read (normal cached, L2-absorbed broadcast) at step n.
#define RING_SLOT_F 16384L

// ---------------------------------------------------------------------------
// Coherent (MALL-point) helpers. sc0 sc1 = bypass L1/L2, serve at LLC.
// Lessons r2/r3: never bulk data through these. Lesson r6/r7: UC-poll spin
// time must be bounded to barrier skew -- ONE poll site per step, after all
// step work; polled lines written ONLY by st_coh (clean), never RMW'd.
// ---------------------------------------------------------------------------
__device__ __forceinline__ void st_coh(float* p, float v)
{
    asm volatile("global_store_dword %0, %1, off sc0 sc1"
                 :: "v"(p), "v"(v) : "memory");
}

__device__ __forceinline__ void st_coh_u32(unsigned* p, unsigned v)
{
    asm volatile("global_store_dword %0, %1, off sc0 sc1"
                 :: "v"(p), "v"(v) : "memory");
}

__device__ __forceinline__ unsigned ld_coh_u32(const unsigned* p)
{
    unsigned v;
    asm volatile("global_load_dword %0, %1, off sc0 sc1\n\t"
                 "s_waitcnt vmcnt(0)"
                 : "=v"(v) : "v"(p) : "memory");
    return v;
}

__host__ __device__ __forceinline__ float* ring_slot(float* R, int n)
{
    long off;
    if (n < 248)      off = 30539776L + (long)n * RING_SLOT_F;        // Hall..TAIL gap
    else if (n < 444) off = 4259840L + (long)(n - 248) * RING_SLOT_F; // dead G2 (past BAR)
    else              off = 2244608L + (long)(n - 444) * RING_SLOT_F; // dead WEFF_t tail
    return R + off;
}

// ---------------------------------------------------------------------------
// gemm128 v2: fp32, 128x128 tile, 256 thr, 8x8 micro, DOUBLE-BUFFERED LDS:
// next k-tile loaded to registers during compute of current tile; one sync
// per tile instead of two. Per-output FMA order unchanged -> bitwise
// identical results to the verified v1.
// ---------------------------------------------------------------------------
__global__ __launch_bounds__(256) void gemm128(
    const float* __restrict__ A, const float* __restrict__ Bm,
    float* __restrict__ C, int M, int N, int K,
    const float* __restrict__ bias, const float* __restrict__ res,
    const int* __restrict__ posidx, const float* __restrict__ postab,
    int relu)
{
    __shared__ float As[2][16 * 132];
    __shared__ float Bs[2][16 * 132];
    int m0 = blockIdx.x * 128, n0 = blockIdx.y * 128;
    int tid = threadIdx.x;
    int tx = tid & 15, ty = tid >> 4;
    float acc[8][8];
#pragma unroll
    for (int i = 0; i < 8; ++i)
#pragma unroll
        for (int j = 0; j < 8; ++j) acc[i][j] = 0.f;

    float ra[8], rb[8];
    auto loadA = [&](int k0) {
#pragma unroll
        for (int i = 0; i < 8; ++i) {             // A: 128 m x 16 k
            int idx = i * 256 + tid;
            int m = idx >> 4, kl = idx & 15;
            int r = m0 + m, k = k0 + kl;
            ra[i] = (r < M && k < K) ? A[(long)r * K + k] : 0.f;
        }
    };
    auto loadB = [&](int k0) {
#pragma unroll
        for (int i = 0; i < 8; ++i) {             // B: 16 k x 128 n
            int idx = i * 256 + tid;
            int n = idx & 127, k = idx >> 7;
            int kk = k0 + k, nn = n0 + n;
            rb[i] = (kk < K && nn < N) ? Bm[(long)kk * N + nn] : 0.f;
        }
    };

    loadA(0); loadB(0);
    int cur = 0;
    for (int k0 = 0; k0 < K; k0 += 16) {
#pragma unroll
        for (int i = 0; i < 8; ++i) {
            int idx = i * 256 + tid;
            As[cur][(idx & 15) * 132 + (idx >> 4)] = ra[i];
        }
#pragma unroll
        for (int i = 0; i < 8; ++i) {
            int idx = i * 256 + tid;
            Bs[cur][(idx >> 7) * 132 + (idx & 127)] = rb[i];
        }
        __syncthreads();
        if (k0 + 16 < K) { loadA(k0 + 16); loadB(k0 + 16); }  // overlap w/ compute
#pragma unroll
        for (int kk = 0; kk < 16; ++kk) {
            float4 a0 = *(const float4*)&As[cur][kk * 132 + ty * 4];
            float4 a1 = *(const float4*)&As[cur][kk * 132 + 64 + ty * 4];
            float4 b0 = *(const float4*)&Bs[cur][kk * 132 + tx * 4];
            float4 b1 = *(const float4*)&Bs[cur][kk * 132 + 64 + tx * 4];
            float a[8] = {a0.x, a0.y, a0.z, a0.w, a1.x, a1.y, a1.z, a1.w};
            float b[8] = {b0.x, b0.y, b0.z, b0.w, b1.x, b1.y, b1.z, b1.w};
#pragma unroll
            for (int i = 0; i < 8; ++i)
#pragma unroll
                for (int j = 0; j < 8; ++j) acc[i][j] += a[i] * b[j];
        }
        cur ^= 1;   // writes next iter go to the other buffer (no 2nd sync)
    }
#pragma unroll
    for (int i = 0; i < 8; ++i) {
        int m = m0 + ((i < 4) ? (ty * 4 + i) : (64 + ty * 4 + i - 4));
        if (m >= M) continue;
#pragma unroll
        for (int j = 0; j < 8; ++j) {
            int n = n0 + ((j < 4) ? (tx * 4 + j) : (64 + tx * 4 + j - 4));
            if (n >= N) continue;
            float v = acc[i][j];
            if (bias) v += bias[n];
            if (res) v += res[(long)m * N + n];
            if (posidx) v += postab[(long)posidx[m] * N + n];
            if (relu) v = fmaxf(v, 0.f);
            C[(long)m * N + n] = v;
        }
    }
}

// ---------------------------------------------------------------------------
// LayerNorm over last dim N (=800), one block per row.
// ---------------------------------------------------------------------------
__global__ __launch_bounds__(256) void ln_f32(
    const float* __restrict__ X, float* __restrict__ Y,
    const float* __restrict__ g, const float* __restrict__ b, int N)
{
    int m = blockIdx.x;
    const float* x = X + (long)m * N;
    __shared__ float red[256];
    int tid = threadIdx.x;
    float s = 0.f;
    for (int i = tid; i < N; i += 256) s += x[i];
    red[tid] = s; __syncthreads();
    for (int o = 128; o > 0; o >>= 1) { if (tid < o) red[tid] += red[tid + o]; __syncthreads(); }
    float mean = red[0] / N;
    __syncthreads();
    float v = 0.f;
    for (int i = tid; i < N; i += 256) { float d = x[i] - mean; v += d * d; }
    red[tid] = v; __syncthreads();
    for (int o = 128; o > 0; o >>= 1) { if (tid < o) red[tid] += red[tid + o]; __syncthreads(); }
    float rs = rsqrtf(red[0] / N + 1e-6f);
    for (int i = tid; i < N; i += 256)
        Y[(long)m * N + i] = (x[i] - mean) * rs * g[i] + b[i];
}

// ---------------------------------------------------------------------------
// Fused banded attention (verified round 1).
// ---------------------------------------------------------------------------
__global__ __launch_bounds__(256) void attn_f32(
    const float* __restrict__ Q, const float* __restrict__ K,
    const float* __restrict__ V, float* __restrict__ O)
{
    int blk = blockIdx.x;
    int qt = blk & 127; int bh = blk >> 7;
    int h = bh & 7; int b = bh >> 3;
    int q0 = qt * 4;
    int tid = threadIdx.x;

    __shared__ float qv[4][DH_];
    __shared__ float sc[4][208];
    __shared__ float red[256];
    __shared__ float inv_den[4];

    for (int i = tid; i < 4 * DH_; i += 256) {
        int qi = i / DH_, d = i - qi * DH_;
        qv[qi][d] = Q[(long)(b * S_ + q0 + qi) * DM_ + h * DH_ + d];
    }
    __syncthreads();

    int w = tid;
    int k = q0 - WIN_ + w;
    bool kvalid = (w < 204) && (k >= 0) && (k < S_);
    float dots[4] = {0.f, 0.f, 0.f, 0.f};
    if (kvalid) {
        const float* krow = K + (long)(b * S_ + k) * DM_ + h * DH_;
        for (int d = 0; d < DH_; ++d) {
            float kvv = krow[d];
#pragma unroll
            for (int qi = 0; qi < 4; ++qi) dots[qi] += qv[qi][d] * kvv;
        }
    }
#pragma unroll
    for (int qi = 0; qi < 4; ++qi) {
        int wq = w - qi;
        if (w < 204 && wq >= 0 && wq < 201)
            sc[qi][wq] = kvalid ? dots[qi] * 0.1f : -1e30f;
    }
    __syncthreads();

    for (int qi = 0; qi < 4; ++qi) {
        float vmax = (tid < 201) ? sc[qi][tid] : -1e30f;
        red[tid] = vmax; __syncthreads();
        for (int o = 128; o > 0; o >>= 1) { if (tid < o) red[tid] = fmaxf(red[tid], red[tid + o]); __syncthreads(); }
        float mx = red[0];
        __syncthreads();
        float e = 0.f;
        if (tid < 201) { e = __expf(sc[qi][tid] - mx); sc[qi][tid] = e; }
        red[tid] = e; __syncthreads();
        for (int o = 128; o > 0; o >>= 1) { if (tid < o) red[tid] += red[tid + o]; __syncthreads(); }
        if (tid == 0) inv_den[qi] = 1.f / red[0];
        __syncthreads();
    }

    if (tid < DH_) {
        int d = tid;
        float o_[4] = {0.f, 0.f, 0.f, 0.f};
        for (int w2 = 0; w2 < 204; ++w2) {
            int k2 = q0 - WIN_ + w2;
            if (k2 < 0 || k2 >= S_) continue;
            float vv = V[(long)(b * S_ + k2) * DM_ + h * DH_ + d];
#pragma unroll
            for (int qi = 0; qi < 4; ++qi) {
                int wq = w2 - qi;
                if (wq >= 0 && wq < 201) o_[qi] += sc[qi][wq] * vv;
            }
        }
#pragma unroll
        for (int qi = 0; qi < 4; ++qi)
            O[(long)(b * S_ + q0 + qi) * DM_ + h * DH_ + d] = o_[qi] * inv_den[qi];
    }
}

// g3[j] = out_b @ Wx
__global__ __launch_bounds__(256) void g3_kernel(
    const float* __restrict__ outb, const float* __restrict__ Wx, float* __restrict__ g3)
{
    int j = blockIdx.x * 256 + threadIdx.x;
    if (j >= G4_) return;
    float s = 0.f;
    for (int p = 0; p < POSE_; ++p) s += outb[p] * Wx[(long)p * G4_ + j];
    g3[j] = s;
}

// init h state into ring slot 0 (TRANSPOSED: [hid][16]) + zero sync state
__global__ __launch_bounds__(256) void init_state(
    const float* __restrict__ vh, float* __restrict__ ring0,
    unsigned* __restrict__ bar)
{
    int i = blockIdx.x * 256 + threadIdx.x;
    if (i < B_ * HID_) {
        int bb = i >> 10, hid = i & 1023;
        ring0[hid * 16 + bb] = vh[i];
    }
    if (i < 4096) bar[i] = 0u;
}

// ---------------------------------------------------------------------------
// xb_gather: pack ENC rows needed by B-steps into XB[s*16+b][800].
// ---------------------------------------------------------------------------
__global__ __launch_bounds__(256) void xb_gather(
    const float* __restrict__ X, float* __restrict__ XB,
    const int* __restrict__ epoch)
{
    long idx = (long)blockIdx.x * 256 + threadIdx.x;   // < NSLOT_*16*800
    int s = (int)(idx / 12800);
    int rem = (int)(idx - (long)s * 12800);
    int bb = rem / 800, k = rem - bb * 800;
    int p = (int)((double)epoch[0] * 0.01);
    float v = 0.f;
    if (p > 0) {
        int per = p + 10;
        int t = (s / p) * per + (s % p);
        if (t >= 1 && t < S_) v = X[((long)bb * S_ + (t - 1)) * DM_ + k];
    }
    XB[idx] = v;
}

// ---------------------------------------------------------------------------
// tr_cat: WT[c][k] = (k<K1 ? in1[k][c] : k<K1+K2 ? in2[k-K1][c] : 0)
// ---------------------------------------------------------------------------
__global__ __launch_bounds__(256) void tr_cat(
    const float* __restrict__ in1, const float* __restrict__ in2,
    float* __restrict__ WT, int K1, int K2, int KP)
{
    __shared__ float tile[64][65];
    int k0 = blockIdx.x * 64, c0 = blockIdx.y * 64;
    int tid = threadIdx.x;
    int cl = tid & 63, kr = tid >> 6;
#pragma unroll
    for (int i = 0; i < 16; ++i) {
        int kl = i * 4 + kr;
        int k = k0 + kl, c = c0 + cl;
        float v = 0.f;
        if (k < K1) v = in1[(long)k * G4_ + c];
        else if (k < K1 + K2) v = in2[(long)(k - K1) * G4_ + c];
        tile[kl][cl] = v;
    }
    __syncthreads();
    int kl2 = tid & 63, cr = tid >> 6;
#pragma unroll
    for (int i = 0; i < 16; ++i) {
        int ci = i * 4 + cr;
        WT[(long)(c0 + ci) * KP + k0 + kl2] = tile[kl2][ci];
    }
}

// ---------------------------------------------------------------------------
// lstm_scan v8 = r8's verified split-barrier structure + DUAL-PAN LDS:
// two 17.4 KB panels ping-pong so LDS staging of panel g+1 overlaps the FMA
// of panel g; 5 post-wait syncthreads instead of 8. Per-thread FMA order
// unchanged -> bitwise identical to r8. LDS 77.8 KB static (gfx950: 160 KB/CU)
// -> still 2 blocks/CU, 512 blocks co-resident.
// Sync: r5/r8-proven chain (16-wide group RMW -> root RMW -> 32 clean gen
// replicas; ONE poll/step at first h use).
// ---------------------------------------------------------------------------
__global__ __launch_bounds__(256, 2) void lstm_scan(
    float* __restrict__ Rbase,
    const float* __restrict__ vec_c,
    const float* __restrict__ WT_A, const float* __restrict__ WT_Bh,
    const float* __restrict__ g3, const float* __restrict__ lstm_b,
    const int* __restrict__ epoch,
    const float* __restrict__ tgt, const float* __restrict__ dec0,
    const float* __restrict__ ENCB, float* __restrict__ Hall,
    unsigned* __restrict__ bar)
{
    __shared__ float WL[WLSZ_];        // 8 WT_A rows, stride WLS_
    __shared__ float panA[256 * 17];   // ping
    __shared__ float panB[256 * 17];   // pong
    float* red = panA;                 // reduce scratch aliases panA
    float* gst = panA + 2304;

    int tid = threadIdx.x;
    int hid0 = blockIdx.x * 2;
    int kq = tid >> 4, b = tid & 15;
    int b3 = tid >> 1, hh = tid & 1;
    int p = (int)((double)epoch[0] * 0.01);   // match python int(epoch*LAMB)
    int per = p + 10;
    unsigned grp = (unsigned)blockIdx.x >> 4;  // 32 groups x 16 blocks
    unsigned* gcnt = bar;                      // 32 RMW lines (never polled)
    unsigned* root = bar + 1024;               // 1 RMW line  (never polled)
    unsigned* genA = bar + 1056;               // 32 clean replicas (st_coh only)

    // ---- one-time: stage this block's 8 WT_A rows into LDS ----
#pragma unroll
    for (int c = 0; c < 8; ++c) {
        const float* src = WT_A + (long)((c >> 1) * 1024 + hid0 + (c & 1)) * KPA_;
        for (int i = tid * 4; i < WLS_; i += 1024)
            *(float4*)&WL[c * WLS_ + i] = *(const float4*)&src[i];
    }
    for (int i = 8 * WLS_ + tid; i < WLSZ_; i += 256) WL[i] = 0.f;  // NaN guard

    float c_reg = 0.f;
    if (tid < 32) c_reg = vec_c[b3 * HID_ + hid0 + hh];
    __syncthreads();

    for (int t = 0; t < S_; ++t) {
        bool msk = (t % per) >= p;
        bool useA = msk || (t == 0);
        const float* hrd = ring_slot(Rbase, t);
        float*       hwr = ring_slot(Rbase, t + 1);

        float acc[8]  = {0.f, 0.f, 0.f, 0.f, 0.f, 0.f, 0.f, 0.f};
        float acc2[8] = {0.f, 0.f, 0.f, 0.f, 0.f, 0.f, 0.f, 0.f};

        auto fma_wl = [&](int P, float* a, const float* pn) {
            int kb = P + kq * 16;
#pragma unroll
            for (int j4 = 0; j4 < 4; ++j4) {
                float4 w[8];
#pragma unroll
                for (int c = 0; c < 8; ++c)
                    w[c] = *(const float4*)&WL[c * WLS_ + kb + j4 * 4];
                float h0 = pn[(kq * 16 + j4 * 4 + 0) * 17 + b];
                float h1 = pn[(kq * 16 + j4 * 4 + 1) * 17 + b];
                float h2 = pn[(kq * 16 + j4 * 4 + 2) * 17 + b];
                float h3 = pn[(kq * 16 + j4 * 4 + 3) * 17 + b];
#pragma unroll
                for (int c = 0; c < 8; ++c)
                    a[c] += w[c].x * h0 + w[c].y * h1 + w[c].z * h2 + w[c].w * h3;
            }
        };
        auto loadh4 = [&](float4 v[4], int P) {
            const float* q = hrd + (long)(P + tid) * 16;
            v[0] = *(const float4*)(q);      v[1] = *(const float4*)(q + 4);
            v[2] = *(const float4*)(q + 8);  v[3] = *(const float4*)(q + 12);
        };
        auto writecol = [&](const float4 v[4], float* pn) {  // pn[k=tid][b]
            float* pp = &pn[tid * 17];
            pp[0]=v[0].x;  pp[1]=v[0].y;  pp[2]=v[0].z;  pp[3]=v[0].w;
            pp[4]=v[1].x;  pp[5]=v[1].y;  pp[6]=v[1].z;  pp[7]=v[1].w;
            pp[8]=v[2].x;  pp[9]=v[2].y;  pp[10]=v[2].z; pp[11]=v[2].w;
            pp[12]=v[3].x; pp[13]=v[3].y; pp[14]=v[3].z; pp[15]=v[3].w;
        };

        // ---- 1. issue tgt/dec0 prefetch (independent of h) ----
        float tp4[16], tp5[16];
        if (useA) {
#pragma unroll
            for (int bb = 0; bb < 16; ++bb) {
                const float* src = msk ? &tgt[((long)bb * S_ + t) * POSE_]
                                       : &dec0[(long)bb * POSE_];
                tp4[bb] = src[tid];                              // tid<256<274
                tp5[bb] = (tid < POSE_ - 256) ? src[256 + tid] : 0.f;
            }
        }

        if (useA) {
            // ---- 2. tgt FMA phases into acc2 (no h dependence); dual pan ----
#pragma unroll
            for (int bb = 0; bb < 16; ++bb) panA[tid * 17 + bb] = tp4[bb];
            __syncthreads();
#pragma unroll
            for (int bb = 0; bb < 16; ++bb) panB[tid * 17 + bb] = tp5[bb];
            fma_wl(1024, acc2, panA);
            __syncthreads();
            fma_wl(1280, acc2, panB);
        }

        // ---- 3. WAIT for h_t (one poll site/step; clean replica line) ----
        if (t > 0) {
            if (tid == 0)
                while (ld_coh_u32(&genA[grp * 32]) < (unsigned)t)
                    __builtin_amdgcn_s_sleep(2);
            __syncthreads();
        }

        // ---- 4. h phases: 4 panels in one load batch; pan ping-pong ----
        float4 hA[4], hB[4], hC[4], hD[4];
        loadh4(hA, 0); loadh4(hB, 256); loadh4(hC, 512); loadh4(hD, 768);
        if (useA) {
            writecol(hA, panA); __syncthreads();
            writecol(hB, panB); fma_wl(0, acc, panA);   __syncthreads();
            writecol(hC, panA); fma_wl(256, acc, panB); __syncthreads();
            writecol(hD, panB); fma_wl(512, acc, panA); __syncthreads();
            fma_wl(768, acc, panB); __syncthreads();
        } else {
            const float* wrow[8];
#pragma unroll
            for (int c = 0; c < 8; ++c)
                wrow[c] = WT_Bh + (long)((c >> 1) * 1024 + hid0 + (c & 1)) * KPB_;
            auto fmaB = [&](int P, const float* pn) {
                int kb = P + kq * 16;
#pragma unroll
                for (int j4 = 0; j4 < 4; ++j4) {
                    float4 w[8];
#pragma unroll
                    for (int c = 0; c < 8; ++c)
                        w[c] = *(const float4*)(wrow[c] + kb + j4 * 4);
                    float h0 = pn[(kq * 16 + j4 * 4 + 0) * 17 + b];
                    float h1 = pn[(kq * 16 + j4 * 4 + 1) * 17 + b];
                    float h2 = pn[(kq * 16 + j4 * 4 + 2) * 17 + b];
                    float h3 = pn[(kq * 16 + j4 * 4 + 3) * 17 + b];
#pragma unroll
                    for (int c = 0; c < 8; ++c)
                        acc[c] += w[c].x * h0 + w[c].y * h1 + w[c].z * h2 + w[c].w * h3;
                }
            };
            writecol(hA, panA); __syncthreads();
            writecol(hB, panB); fmaB(0, panA);   __syncthreads();
            writecol(hC, panA); fmaB(256, panB); __syncthreads();
            writecol(hD, panB); fmaB(512, panA); __syncthreads();
            fmaB(768, panB); __syncthreads();
        }

        // ---- 5. reduce 16 k-slices (panA free; red aliases it) ----
#pragma unroll
        for (int c = 0; c < 8; ++c) red[(b * 16 + kq) * 9 + c] = acc[c] + acc2[c];
        __syncthreads();

        if (tid < 128) {
            int ob = tid >> 3, oc = tid & 7;
            float s = 0.f;
#pragma unroll
            for (int q = 0; q < 16; ++q) s += red[(ob * 16 + q) * 9 + oc];
            int gcol = (oc >> 1) * 1024 + hid0 + (oc & 1);
            s += lstm_b[gcol];
            if (!useA) {
                int sidx = ((t / per) * p + (t % per)) & (NSLOT_ - 1);
                s += g3[gcol] + ENCB[((long)(sidx * 16 + ob)) * G4_ + gcol];
            }
            gst[oc * 16 + ob] = s;
        }
        __syncthreads();

        if (tid < 32) {
            int hid = hid0 + hh;
            float iv = gst[(0 * 2 + hh) * 16 + b3];
            float fv = gst[(1 * 2 + hh) * 16 + b3];
            float gv = gst[(2 * 2 + hh) * 16 + b3];
            float ov = gst[(3 * 2 + hh) * 16 + b3];
            float ig = 1.f / (1.f + __expf(-iv));
            float fg = 1.f / (1.f + __expf(-fv));
            float og = 1.f / (1.f + __expf(-ov));
            float cn = fg * c_reg + ig * tanhf(gv);
            float hn = og * tanhf(cn);
            c_reg = cn;
            st_coh(&hwr[hid * 16 + b3], hn);               // write-through to MALL
            Hall[((long)b3 * S_ + t) * HID_ + hid] = hn;   // normal store
        }

        // ---- 6. ARRIVE (r5-proven chain; wave 0, vmcnt covers h stores) ----
        if (tid == 0) {
            asm volatile("s_waitcnt vmcnt(0)" ::: "memory");
            unsigned tk = __hip_atomic_fetch_add(&gcnt[grp * 32], 1u,
                              __ATOMIC_RELAXED, __HIP_MEMORY_SCOPE_AGENT);
            if (tk == (unsigned)(16 * t + 15)) {            // last in group
                unsigned r = __hip_atomic_fetch_add(root, 1u,
                                 __ATOMIC_RELAXED, __HIP_MEMORY_SCOPE_AGENT);
                if (r == (unsigned)(32 * t + 31)) {         // last group
#pragma unroll
                    for (int j = 0; j < 32; ++j)
                        st_coh_u32(&genA[j * 32], (unsigned)(t + 1));
                }
            }
        }
        __syncthreads();   // protects panA (gst) from next step's tgt staging
    }
}

// ---------------------------------------------------------------------------
extern "C" void kernel_launch(void* const* d_in, const int* in_sizes, int n_in,
                              void* d_out, int out_size, void* d_ws, size_t ws_size,
                              hipStream_t stream) {
    const float* src_seq  = (const float*)d_in[0];
    const int*   src_pos  = (const int*)  d_in[1];
    const float* tgt_seq  = (const float*)d_in[2];
    const float* vec_h    = (const float*)d_in[3];
    const float* vec_c    = (const float*)d_in[4];
    const float* dec0     = (const float*)d_in[5];
    const float* emb_W    = (const float*)d_in[6];
    const float* emb_b    = (const float*)d_in[7];
    const float* pos_tab  = (const float*)d_in[8];
    const float* Wq       = (const float*)d_in[9];
    const float* Wk       = (const float*)d_in[10];
    const float* Wv       = (const float*)d_in[11];
    const float* Wo       = (const float*)d_in[12];
    const float* ln1_g    = (const float*)d_in[13];
    const float* ln1_b    = (const float*)d_in[14];
    const float* ffn_W1   = (const float*)d_in[15];
    const float* ffn_b1   = (const float*)d_in[16];
    const float* ffn_W2   = (const float*)d_in[17];
    const float* ffn_b2   = (const float*)d_in[18];
    const float* ln2_g    = (const float*)d_in[19];
    const float* ln2_b    = (const float*)d_in[20];
    const float* lstm_Wx  = (const float*)d_in[21];
    const float* lstm_Wh  = (const float*)d_in[22];
    const float* lstm_b   = (const float*)d_in[23];
    const float* out_W    = (const float*)d_in[24];
    const float* out_b    = (const float*)d_in[25];
    const int*   epoch    = (const int*)  d_in[26];

    // ---- workspace layout (total 41,209,856 floats = 164.8 MB) ----
    float* ws = (float*)d_ws;
    const long NX = (long)B_ * S_ * DM_;           // 6,553,600
    float* X      = ws;                            // enc / residual [0, NX)
    float* R      = X + NX;                        // 34,603,008-float region
    // encoder phase:
    float* Qb     = R;
    float* Kb     = Qb + NX;
    float* Vb     = Kb + NX;
    float* Ob     = Vb + NX;
    float* FFNH   = Ob + NX;                       // 8,388,608
    // decoder phase (aliases into R; encoder scratch dead):
    float* WEFF_t = R;                             // [0, 4,194,304)
    float* G2m    = R + 4194304;                   // 800x4096 (dead after ENCB gemm)
    float* WT_A   = R + 7471104;                   // 4096 x 1536
    float* WT_B   = R + 13762560;                  // 4096 x 1024 (WEFF^T only)
    float* ENCB   = R + 17956864;                  // 64*16 x 4096 (B-step enc@G2)
    float* Hall   = R + 22151168;                  // B*S x 1024
    float* T1     = WEFF_t;                        // 2,244,608 (after tr_cat B)
    float* XB     = R + 3375104;                   // 64*16 x 800 gather buffer
    float* TAIL   = R + 34603008;
    float* G3v    = TAIL;                          // 4096
    // h-ring (ring_slot): [R+30539776,+248*16K) ; [R+4259840,+196*16K) ;
    //                     [R+2244608,+69*16K). All scan-dead; each addr once.
    unsigned* BAR = (unsigned*)G2m;                // sync lines (zeroed post-ENCB)

    const int M = B_ * S_; // 8192
    dim3 blk(256);

    // ---- encoder ----
    gemm128<<<dim3(M / 128, (DM_ + 127) / 128), blk, 0, stream>>>(
        src_seq, emb_W, X, M, DM_, FRAME_, emb_b, nullptr, src_pos, pos_tab, 0);
    gemm128<<<dim3(M / 128, (DM_ + 127) / 128), blk, 0, stream>>>(
        X, Wq, Qb, M, DM_, DM_, nullptr, nullptr, nullptr, nullptr, 0);
    gemm128<<<dim3(M / 128, (DM_ + 127) / 128), blk, 0, stream>>>(
        X, Wk, Kb, M, DM_, DM_, nullptr, nullptr, nullptr, nullptr, 0);
    gemm128<<<dim3(M / 128, (DM_ + 127) / 128), blk, 0, stream>>>(
        X, Wv, Vb, M, DM_, DM_, nullptr, nullptr, nullptr, nullptr, 0);
    attn_f32<<<dim3(B_ * H_ * (S_ / 4)), blk, 0, stream>>>(Qb, Kb, Vb, Ob);
    gemm128<<<dim3(M / 128, (DM_ + 127) / 128), blk, 0, stream>>>(
        Ob, Wo, FFNH, M, DM_, DM_, nullptr, X, nullptr, nullptr, 0);
    ln_f32<<<dim3(M), blk, 0, stream>>>(FFNH, X, ln1_g, ln1_b, DM_);
    gemm128<<<dim3(M / 128, FFN_ / 128), blk, 0, stream>>>(
        X, ffn_W1, FFNH, M, FFN_, DM_, ffn_b1, nullptr, nullptr, nullptr, 1);
    gemm128<<<dim3(M / 128, (DM_ + 127) / 128), blk, 0, stream>>>(
        FFNH, ffn_W2, Ob, M, DM_, FFN_, ffn_b2, X, nullptr, nullptr, 0);
    ln_f32<<<dim3(M), blk, 0, stream>>>(Ob, X, ln2_g, ln2_b, DM_);   // X = enc

    // ---- decoder precompute ----
    gemm128<<<dim3(HID_ / 128, G4_ / 128), blk, 0, stream>>>(
        out_W, lstm_Wx, WEFF_t, HID_, G4_, POSE_, nullptr, lstm_Wh, nullptr, nullptr, 0);
    gemm128<<<dim3((DM_ + 127) / 128, G4_ / 128), blk, 0, stream>>>(
        out_W + (long)HID_ * POSE_, lstm_Wx, G2m, DM_, G4_, POSE_,
        nullptr, nullptr, nullptr, nullptr, 0);
    tr_cat<<<dim3(KPA_ / 64, G4_ / 64), blk, 0, stream>>>(
        lstm_Wh, lstm_Wx, WT_A, HID_, POSE_, KPA_);
    tr_cat<<<dim3(KPB_ / 64, G4_ / 64), blk, 0, stream>>>(
        WEFF_t, WEFF_t, WT_B, HID_, 0, KPB_);      // WEFF^T only
    xb_gather<<<dim3(NSLOT_ * 16 * 800 / 256), blk, 0, stream>>>(X, XB, epoch);
    g3_kernel<<<dim3(G4_ / 256), blk, 0, stream>>>(out_b, lstm_Wx, G3v);
    // ENCB = XB @ G2m  (reads G2m -> must precede init_state's BAR zeroing)
    gemm128<<<dim3(NSLOT_ * 16 / 128, G4_ / 128), blk, 0, stream>>>(
        XB, G2m, ENCB, NSLOT_ * 16, G4_, DM_, nullptr, nullptr, nullptr, nullptr, 0);
    init_state<<<dim3((B_ * HID_ + 255) / 256), blk, 0, stream>>>(
        vec_h, ring_slot(R, 0), BAR);
    gemm128<<<dim3(M / 128, (POSE_ + 127) / 128), blk, 0, stream>>>(
        X, out_W + (long)HID_ * POSE_, T1, M, POSE_, DM_, out_b,
        nullptr, nullptr, nullptr, 0);

    // ---- fused sequential scan: split barrier + dual-pan LDS overlap ----
    lstm_scan<<<dim3(NBLK_SCAN), blk, 0, stream>>>(
        R, vec_c, WT_A, WT_B, G3v, lstm_b, epoch,
        tgt_seq, dec0, ENCB, Hall, BAR);

    // ---- final: out = Hall@out_W[:1024] + T1 ----
    gemm128<<<dim3(M / 128, (POSE_ + 127) / 128), blk, 0, stream>>>(
        Hall, out_W, (float*)d_out, M, POSE_, HID_, nullptr, T1,
        nullptr, nullptr, 0);
}

// Round 10
// 8982.221 us; speedup vs baseline: 2.2884x; 1.0668x over previous
//
#include <hip/hip_runtime.h>
#include <math.h>

#define B_ 16
#define S_ 512
#define FRAME_ 438
#define DM_ 800
#define H_ 8
#define DH_ 100
#define FFN_ 1024
#define HID_ 1024
#define POSE_ 274
#define WIN_ 100
#define G4_ 4096     // 4*HID
#define KPA_ 1536    // padded K for WT_A ([Wh;Wx], K=1298)
#define KPB_ 1024    // K for WT_B (WEFF^T only; enc part precomputed in ENCB)
#define NBLK_SCAN 512
#define WLS_ 1312    // LDS row stride for WT_A slice (>=1298, mult of 4)
#define WLSZ_ (8 * WLS_ + 256)  // + zero tail (guards row-7 k>=1312 reads; h/tgt=0 there)
#define NSLOT_ 64    // ENCB slots (46 needed at epoch=100)

// h-ring: 513 slots x 16384 floats (64 KB), layout [b][hid] (natural).
// Slot n holds h after step n-1. Addresses used ONCE: written (sc0/sc1->MALL)
// at step n-1, read (normal cached, L2-absorbed broadcast) at step n.
#define RING_SLOT_F 16384L

// ---------------------------------------------------------------------------
// Coherent (MALL-point) helpers. sc0 sc1 = bypass L1/L2, serve at LLC.
// Lessons r2/r3: never bulk data through these. Lesson r6/r7: UC-poll spin
// time must be bounded to barrier skew -- ONE poll site per step, after all
// step work; polled lines written ONLY by st_coh (clean), never RMW'd.
// ---------------------------------------------------------------------------
__device__ __forceinline__ void st_coh(float* p, float v)
{
    asm volatile("global_store_dword %0, %1, off sc0 sc1"
                 :: "v"(p), "v"(v) : "memory");
}

__device__ __forceinline__ void st_coh_u32(unsigned* p, unsigned v)
{
    asm volatile("global_store_dword %0, %1, off sc0 sc1"
                 :: "v"(p), "v"(v) : "memory");
}

__device__ __forceinline__ unsigned ld_coh_u32(const unsigned* p)
{
    unsigned v;
    asm volatile("global_load_dword %0, %1, off sc0 sc1\n\t"
                 "s_waitcnt vmcnt(0)"
                 : "=v"(v) : "v"(p) : "memory");
    return v;
}

__host__ __device__ __forceinline__ float* ring_slot(float* R, int n)
{
    long off;
    if (n < 248)      off = 30539776L + (long)n * RING_SLOT_F;        // Hall..TAIL gap
    else if (n < 444) off = 4259840L + (long)(n - 248) * RING_SLOT_F; // dead G2 (past BAR)
    else              off = 2244608L + (long)(n - 444) * RING_SLOT_F; // dead WEFF_t tail
    return R + off;
}

// ---------------------------------------------------------------------------
// gemm128 v2: fp32, 128x128 tile, 256 thr, 8x8 micro, DOUBLE-BUFFERED LDS
// (r9-verified). Per-output FMA order identical to v1.
// ---------------------------------------------------------------------------
__global__ __launch_bounds__(256) void gemm128(
    const float* __restrict__ A, const float* __restrict__ Bm,
    float* __restrict__ C, int M, int N, int K,
    const float* __restrict__ bias, const float* __restrict__ res,
    const int* __restrict__ posidx, const float* __restrict__ postab,
    int relu)
{
    __shared__ float As[2][16 * 132];
    __shared__ float Bs[2][16 * 132];
    int m0 = blockIdx.x * 128, n0 = blockIdx.y * 128;
    int tid = threadIdx.x;
    int tx = tid & 15, ty = tid >> 4;
    float acc[8][8];
#pragma unroll
    for (int i = 0; i < 8; ++i)
#pragma unroll
        for (int j = 0; j < 8; ++j) acc[i][j] = 0.f;

    float ra[8], rb[8];
    auto loadA = [&](int k0) {
#pragma unroll
        for (int i = 0; i < 8; ++i) {             // A: 128 m x 16 k
            int idx = i * 256 + tid;
            int m = idx >> 4, kl = idx & 15;
            int r = m0 + m, k = k0 + kl;
            ra[i] = (r < M && k < K) ? A[(long)r * K + k] : 0.f;
        }
    };
    auto loadB = [&](int k0) {
#pragma unroll
        for (int i = 0; i < 8; ++i) {             // B: 16 k x 128 n
            int idx = i * 256 + tid;
            int n = idx & 127, k = idx >> 7;
            int kk = k0 + k, nn = n0 + n;
            rb[i] = (kk < K && nn < N) ? Bm[(long)kk * N + nn] : 0.f;
        }
    };

    loadA(0); loadB(0);
    int cur = 0;
    for (int k0 = 0; k0 < K; k0 += 16) {
#pragma unroll
        for (int i = 0; i < 8; ++i) {
            int idx = i * 256 + tid;
            As[cur][(idx & 15) * 132 + (idx >> 4)] = ra[i];
        }
#pragma unroll
        for (int i = 0; i < 8; ++i) {
            int idx = i * 256 + tid;
            Bs[cur][(idx >> 7) * 132 + (idx & 127)] = rb[i];
        }
        __syncthreads();
        if (k0 + 16 < K) { loadA(k0 + 16); loadB(k0 + 16); }  // overlap w/ compute
#pragma unroll
        for (int kk = 0; kk < 16; ++kk) {
            float4 a0 = *(const float4*)&As[cur][kk * 132 + ty * 4];
            float4 a1 = *(const float4*)&As[cur][kk * 132 + 64 + ty * 4];
            float4 b0 = *(const float4*)&Bs[cur][kk * 132 + tx * 4];
            float4 b1 = *(const float4*)&Bs[cur][kk * 132 + 64 + tx * 4];
            float a[8] = {a0.x, a0.y, a0.z, a0.w, a1.x, a1.y, a1.z, a1.w};
            float b[8] = {b0.x, b0.y, b0.z, b0.w, b1.x, b1.y, b1.z, b1.w};
#pragma unroll
            for (int i = 0; i < 8; ++i)
#pragma unroll
                for (int j = 0; j < 8; ++j) acc[i][j] += a[i] * b[j];
        }
        cur ^= 1;   // writes next iter go to the other buffer (no 2nd sync)
    }
#pragma unroll
    for (int i = 0; i < 8; ++i) {
        int m = m0 + ((i < 4) ? (ty * 4 + i) : (64 + ty * 4 + i - 4));
        if (m >= M) continue;
#pragma unroll
        for (int j = 0; j < 8; ++j) {
            int n = n0 + ((j < 4) ? (tx * 4 + j) : (64 + tx * 4 + j - 4));
            if (n >= N) continue;
            float v = acc[i][j];
            if (bias) v += bias[n];
            if (res) v += res[(long)m * N + n];
            if (posidx) v += postab[(long)posidx[m] * N + n];
            if (relu) v = fmaxf(v, 0.f);
            C[(long)m * N + n] = v;
        }
    }
}

// ---------------------------------------------------------------------------
// LayerNorm over last dim N (=800), one block per row.
// ---------------------------------------------------------------------------
__global__ __launch_bounds__(256) void ln_f32(
    const float* __restrict__ X, float* __restrict__ Y,
    const float* __restrict__ g, const float* __restrict__ b, int N)
{
    int m = blockIdx.x;
    const float* x = X + (long)m * N;
    __shared__ float red[256];
    int tid = threadIdx.x;
    float s = 0.f;
    for (int i = tid; i < N; i += 256) s += x[i];
    red[tid] = s; __syncthreads();
    for (int o = 128; o > 0; o >>= 1) { if (tid < o) red[tid] += red[tid + o]; __syncthreads(); }
    float mean = red[0] / N;
    __syncthreads();
    float v = 0.f;
    for (int i = tid; i < N; i += 256) { float d = x[i] - mean; v += d * d; }
    red[tid] = v; __syncthreads();
    for (int o = 128; o > 0; o >>= 1) { if (tid < o) red[tid] += red[tid + o]; __syncthreads(); }
    float rs = rsqrtf(red[0] / N + 1e-6f);
    for (int i = tid; i < N; i += 256)
        Y[(long)m * N + i] = (x[i] - mean) * rs * g[i] + b[i];
}

// ---------------------------------------------------------------------------
// Fused banded attention (verified round 1).
// ---------------------------------------------------------------------------
__global__ __launch_bounds__(256) void attn_f32(
    const float* __restrict__ Q, const float* __restrict__ K,
    const float* __restrict__ V, float* __restrict__ O)
{
    int blk = blockIdx.x;
    int qt = blk & 127; int bh = blk >> 7;
    int h = bh & 7; int b = bh >> 3;
    int q0 = qt * 4;
    int tid = threadIdx.x;

    __shared__ float qv[4][DH_];
    __shared__ float sc[4][208];
    __shared__ float red[256];
    __shared__ float inv_den[4];

    for (int i = tid; i < 4 * DH_; i += 256) {
        int qi = i / DH_, d = i - qi * DH_;
        qv[qi][d] = Q[(long)(b * S_ + q0 + qi) * DM_ + h * DH_ + d];
    }
    __syncthreads();

    int w = tid;
    int k = q0 - WIN_ + w;
    bool kvalid = (w < 204) && (k >= 0) && (k < S_);
    float dots[4] = {0.f, 0.f, 0.f, 0.f};
    if (kvalid) {
        const float* krow = K + (long)(b * S_ + k) * DM_ + h * DH_;
        for (int d = 0; d < DH_; ++d) {
            float kvv = krow[d];
#pragma unroll
            for (int qi = 0; qi < 4; ++qi) dots[qi] += qv[qi][d] * kvv;
        }
    }
#pragma unroll
    for (int qi = 0; qi < 4; ++qi) {
        int wq = w - qi;
        if (w < 204 && wq >= 0 && wq < 201)
            sc[qi][wq] = kvalid ? dots[qi] * 0.1f : -1e30f;
    }
    __syncthreads();

    for (int qi = 0; qi < 4; ++qi) {
        float vmax = (tid < 201) ? sc[qi][tid] : -1e30f;
        red[tid] = vmax; __syncthreads();
        for (int o = 128; o > 0; o >>= 1) { if (tid < o) red[tid] = fmaxf(red[tid], red[tid + o]); __syncthreads(); }
        float mx = red[0];
        __syncthreads();
        float e = 0.f;
        if (tid < 201) { e = __expf(sc[qi][tid] - mx); sc[qi][tid] = e; }
        red[tid] = e; __syncthreads();
        for (int o = 128; o > 0; o >>= 1) { if (tid < o) red[tid] += red[tid + o]; __syncthreads(); }
        if (tid == 0) inv_den[qi] = 1.f / red[0];
        __syncthreads();
    }

    if (tid < DH_) {
        int d = tid;
        float o_[4] = {0.f, 0.f, 0.f, 0.f};
        for (int w2 = 0; w2 < 204; ++w2) {
            int k2 = q0 - WIN_ + w2;
            if (k2 < 0 || k2 >= S_) continue;
            float vv = V[(long)(b * S_ + k2) * DM_ + h * DH_ + d];
#pragma unroll
            for (int qi = 0; qi < 4; ++qi) {
                int wq = w2 - qi;
                if (wq >= 0 && wq < 201) o_[qi] += sc[qi][wq] * vv;
            }
        }
#pragma unroll
        for (int qi = 0; qi < 4; ++qi)
            O[(long)(b * S_ + q0 + qi) * DM_ + h * DH_ + d] = o_[qi] * inv_den[qi];
    }
}

// g3[j] = out_b @ Wx
__global__ __launch_bounds__(256) void g3_kernel(
    const float* __restrict__ outb, const float* __restrict__ Wx, float* __restrict__ g3)
{
    int j = blockIdx.x * 256 + threadIdx.x;
    if (j >= G4_) return;
    float s = 0.f;
    for (int p = 0; p < POSE_; ++p) s += outb[p] * Wx[(long)p * G4_ + j];
    g3[j] = s;
}

// init h state into ring slot 0 ([b][hid] natural layout) + zero sync state
__global__ __launch_bounds__(256) void init_state(
    const float* __restrict__ vh, float* __restrict__ ring0,
    unsigned* __restrict__ bar)
{
    int i = blockIdx.x * 256 + threadIdx.x;
    if (i < B_ * HID_) ring0[i] = vh[i];
    if (i < 4096) bar[i] = 0u;
}

// ---------------------------------------------------------------------------
// xb_gather: pack ENC rows needed by B-steps into XB[s*16+b][800].
// ---------------------------------------------------------------------------
__global__ __launch_bounds__(256) void xb_gather(
    const float* __restrict__ X, float* __restrict__ XB,
    const int* __restrict__ epoch)
{
    long idx = (long)blockIdx.x * 256 + threadIdx.x;   // < NSLOT_*16*800
    int s = (int)(idx / 12800);
    int rem = (int)(idx - (long)s * 12800);
    int bb = rem / 800, k = rem - bb * 800;
    int p = (int)((double)epoch[0] * 0.01);
    float v = 0.f;
    if (p > 0) {
        int per = p + 10;
        int t = (s / p) * per + (s % p);
        if (t >= 1 && t < S_) v = X[((long)bb * S_ + (t - 1)) * DM_ + k];
    }
    XB[idx] = v;
}

// ---------------------------------------------------------------------------
// tr_cat: WT[c][k] = (k<K1 ? in1[k][c] : k<K1+K2 ? in2[k-K1][c] : 0)
// ---------------------------------------------------------------------------
__global__ __launch_bounds__(256) void tr_cat(
    const float* __restrict__ in1, const float* __restrict__ in2,
    float* __restrict__ WT, int K1, int K2, int KP)
{
    __shared__ float tile[64][65];
    int k0 = blockIdx.x * 64, c0 = blockIdx.y * 64;
    int tid = threadIdx.x;
    int cl = tid & 63, kr = tid >> 6;
#pragma unroll
    for (int i = 0; i < 16; ++i) {
        int kl = i * 4 + kr;
        int k = k0 + kl, c = c0 + cl;
        float v = 0.f;
        if (k < K1) v = in1[(long)k * G4_ + c];
        else if (k < K1 + K2) v = in2[(long)(k - K1) * G4_ + c];
        tile[kl][cl] = v;
    }
    __syncthreads();
    int kl2 = tid & 63, cr = tid >> 6;
#pragma unroll
    for (int i = 0; i < 16; ++i) {
        int ci = i * 4 + cr;
        WT[(long)(c0 + ci) * KP + k0 + kl2] = tile[kl2][ci];
    }
}

// ---------------------------------------------------------------------------
// lstm_scan v9: REGISTER-DIRECT h/tgt path. Thread (kq,b) consumes exactly
// h[b][kq*16+j] per phase -- contiguous 64 B it now loads straight from the
// ring ([b][hid] layout) into registers. The LDS h round-trip (global->reg->
// LDS->sync->LDS-read, 4 writecols, 8 syncs) is deleted; LDS keeps only the
// WL weight broadcast (same-address = free) + red/gst reduce scratch.
// 3 syncthreads/step (wait, red, gst). Per-thread FMA sequence identical to
// r9 (phases 1024,1280 -> acc2; 0,256,512,768 -> acc; j4 ascending) ->
// bitwise-identical output.
// Sync: r5/r8/r9-proven chain (16-wide group RMW -> root RMW -> 32 clean gen
// replicas; ONE poll/step at first h use).
// LDS: WL 42 KB + red 9 KB + gst 0.5 KB = 51.5 KB.
// ---------------------------------------------------------------------------
__global__ __launch_bounds__(256, 2) void lstm_scan(
    float* __restrict__ Rbase,
    const float* __restrict__ vec_c,
    const float* __restrict__ WT_A, const float* __restrict__ WT_Bh,
    const float* __restrict__ g3, const float* __restrict__ lstm_b,
    const int* __restrict__ epoch,
    const float* __restrict__ tgt, const float* __restrict__ dec0,
    const float* __restrict__ ENCB, float* __restrict__ Hall,
    unsigned* __restrict__ bar)
{
    __shared__ float WL[WLSZ_];       // 8 WT_A rows, stride WLS_
    __shared__ float red[2304];
    __shared__ float gst[128];

    int tid = threadIdx.x;
    int hid0 = blockIdx.x * 2;
    int kq = tid >> 4, b = tid & 15;
    int b3 = tid >> 1, hh = tid & 1;
    int p = (int)((double)epoch[0] * 0.01);   // match python int(epoch*LAMB)
    int per = p + 10;
    unsigned grp = (unsigned)blockIdx.x >> 4;  // 32 groups x 16 blocks
    unsigned* gcnt = bar;                      // 32 RMW lines (never polled)
    unsigned* root = bar + 1024;               // 1 RMW line  (never polled)
    unsigned* genA = bar + 1056;               // 32 clean replicas (st_coh only)

    // ---- one-time: stage this block's 8 WT_A rows into LDS ----
#pragma unroll
    for (int c = 0; c < 8; ++c) {
        const float* src = WT_A + (long)((c >> 1) * 1024 + hid0 + (c & 1)) * KPA_;
        for (int i = tid * 4; i < WLS_; i += 1024)
            *(float4*)&WL[c * WLS_ + i] = *(const float4*)&src[i];
    }
    for (int i = 8 * WLS_ + tid; i < WLSZ_; i += 256) WL[i] = 0.f;  // NaN guard

    float c_reg = 0.f;
    if (tid < 32) c_reg = vec_c[b3 * HID_ + hid0 + hh];
    __syncthreads();

    for (int t = 0; t < S_; ++t) {
        bool msk = (t % per) >= p;
        bool useA = msk || (t == 0);
        const float* hrd = ring_slot(Rbase, t);       // [b][hid]
        float*       hwr = ring_slot(Rbase, t + 1);

        float acc[8]  = {0.f, 0.f, 0.f, 0.f, 0.f, 0.f, 0.f, 0.f};
        float acc2[8] = {0.f, 0.f, 0.f, 0.f, 0.f, 0.f, 0.f, 0.f};

        // ---- 1. pre-wait: tgt/dec0 -> regs -> acc2 (no h, no LDS writes) ----
        if (useA) {
            const float* src = msk ? &tgt[((long)b * S_ + t) * POSE_]
                                   : &dec0[(long)b * POSE_];
            float4 tr4[4];
            float  tv[16];
#pragma unroll
            for (int j4 = 0; j4 < 4; ++j4)
                tr4[j4] = *(const float4*)(src + kq * 16 + j4 * 4);  // k' <= 255
#pragma unroll
            for (int j = 0; j < 16; ++j) {
                int kk = 256 + kq * 16 + j;
                tv[j] = (kk < POSE_) ? src[kk] : 0.f;   // zero beyond 274 (pan semantics)
            }
            // phase 1024 (j4 asc), then phase 1280 (j4 asc) -- r9 order
#pragma unroll
            for (int j4 = 0; j4 < 4; ++j4) {
                float4 w[8];
#pragma unroll
                for (int c = 0; c < 8; ++c)
                    w[c] = *(const float4*)&WL[c * WLS_ + 1024 + kq * 16 + j4 * 4];
                float4 h4 = tr4[j4];
#pragma unroll
                for (int c = 0; c < 8; ++c)
                    acc2[c] += w[c].x * h4.x + w[c].y * h4.y + w[c].z * h4.z + w[c].w * h4.w;
            }
#pragma unroll
            for (int j4 = 0; j4 < 4; ++j4) {
                float4 w[8];
#pragma unroll
                for (int c = 0; c < 8; ++c)
                    w[c] = *(const float4*)&WL[c * WLS_ + 1280 + kq * 16 + j4 * 4];
#pragma unroll
                for (int c = 0; c < 8; ++c)
                    acc2[c] += w[c].x * tv[j4 * 4 + 0] + w[c].y * tv[j4 * 4 + 1]
                             + w[c].z * tv[j4 * 4 + 2] + w[c].w * tv[j4 * 4 + 3];
            }
        }

        // ---- 2. WAIT for h_t (one poll site/step; clean replica line) ----
        if (t > 0) {
            if (tid == 0)
                while (ld_coh_u32(&genA[grp * 32]) < (unsigned)t)
                    __builtin_amdgcn_s_sleep(2);
            __syncthreads();   // S1 (also orders prev step's gst reads vs red writes)
        }

        // ---- 3. h -> regs (16 float4, one batch; L2-absorbed broadcast) ----
        float4 hr[16];
        {
            const float* hb = hrd + (long)b * HID_;
#pragma unroll
            for (int ph = 0; ph < 4; ++ph) {
                const float* q = hb + ph * 256 + kq * 16;
                hr[ph * 4 + 0] = *(const float4*)(q);
                hr[ph * 4 + 1] = *(const float4*)(q + 4);
                hr[ph * 4 + 2] = *(const float4*)(q + 8);
                hr[ph * 4 + 3] = *(const float4*)(q + 12);
            }
        }
        if (useA) {
#pragma unroll
            for (int ph = 0; ph < 4; ++ph) {
                int kb = ph * 256 + kq * 16;
#pragma unroll
                for (int j4 = 0; j4 < 4; ++j4) {
                    float4 w[8];
#pragma unroll
                    for (int c = 0; c < 8; ++c)
                        w[c] = *(const float4*)&WL[c * WLS_ + kb + j4 * 4];
                    float4 h4 = hr[ph * 4 + j4];
#pragma unroll
                    for (int c = 0; c < 8; ++c)
                        acc[c] += w[c].x * h4.x + w[c].y * h4.y + w[c].z * h4.z + w[c].w * h4.w;
                }
            }
        } else {
            const float* wrow[8];
#pragma unroll
            for (int c = 0; c < 8; ++c)
                wrow[c] = WT_Bh + (long)((c >> 1) * 1024 + hid0 + (c & 1)) * KPB_;
#pragma unroll
            for (int ph = 0; ph < 4; ++ph) {
                int kb = ph * 256 + kq * 16;
#pragma unroll
                for (int j4 = 0; j4 < 4; ++j4) {
                    float4 w[8];
#pragma unroll
                    for (int c = 0; c < 8; ++c)
                        w[c] = *(const float4*)(wrow[c] + kb + j4 * 4);
                    float4 h4 = hr[ph * 4 + j4];
#pragma unroll
                    for (int c = 0; c < 8; ++c)
                        acc[c] += w[c].x * h4.x + w[c].y * h4.y + w[c].z * h4.z + w[c].w * h4.w;
                }
            }
        }

        // ---- 4. reduce 16 k-slices ----
#pragma unroll
        for (int c = 0; c < 8; ++c) red[(b * 16 + kq) * 9 + c] = acc[c] + acc2[c];
        __syncthreads();   // S2

        if (tid < 128) {
            int ob = tid >> 3, oc = tid & 7;
            float s = 0.f;
#pragma unroll
            for (int q = 0; q < 16; ++q) s += red[(ob * 16 + q) * 9 + oc];
            int gcol = (oc >> 1) * 1024 + hid0 + (oc & 1);
            s += lstm_b[gcol];
            if (!useA) {
                int sidx = ((t / per) * p + (t % per)) & (NSLOT_ - 1);
                s += g3[gcol] + ENCB[((long)(sidx * 16 + ob)) * G4_ + gcol];
            }
            gst[oc * 16 + ob] = s;
        }
        __syncthreads();   // S3

        if (tid < 32) {
            int hid = hid0 + hh;
            float iv = gst[(0 * 2 + hh) * 16 + b3];
            float fv = gst[(1 * 2 + hh) * 16 + b3];
            float gv = gst[(2 * 2 + hh) * 16 + b3];
            float ov = gst[(3 * 2 + hh) * 16 + b3];
            float ig = 1.f / (1.f + __expf(-iv));
            float fg = 1.f / (1.f + __expf(-fv));
            float og = 1.f / (1.f + __expf(-ov));
            float cn = fg * c_reg + ig * tanhf(gv);
            float hn = og * tanhf(cn);
            c_reg = cn;
            st_coh(&hwr[(long)b3 * HID_ + hid], hn);       // write-through to MALL
            Hall[((long)b3 * S_ + t) * HID_ + hid] = hn;   // normal store
        }

        // ---- 5. ARRIVE (proven chain; wave 0, vmcnt covers h st_coh) ----
        if (tid == 0) {
            asm volatile("s_waitcnt vmcnt(0)" ::: "memory");
            unsigned tk = __hip_atomic_fetch_add(&gcnt[grp * 32], 1u,
                              __ATOMIC_RELAXED, __HIP_MEMORY_SCOPE_AGENT);
            if (tk == (unsigned)(16 * t + 15)) {            // last in group
                unsigned r = __hip_atomic_fetch_add(root, 1u,
                                 __ATOMIC_RELAXED, __HIP_MEMORY_SCOPE_AGENT);
                if (r == (unsigned)(32 * t + 31)) {         // last group
#pragma unroll
                    for (int j = 0; j < 32; ++j)
                        st_coh_u32(&genA[j * 32], (unsigned)(t + 1));
                }
            }
        }
        // no trailing sync needed: next step's pre-wait section touches no LDS;
        // red/gst WAR hazards are ordered by next step's S1 (wait) barrier.
    }
}

// ---------------------------------------------------------------------------
extern "C" void kernel_launch(void* const* d_in, const int* in_sizes, int n_in,
                              void* d_out, int out_size, void* d_ws, size_t ws_size,
                              hipStream_t stream) {
    const float* src_seq  = (const float*)d_in[0];
    const int*   src_pos  = (const int*)  d_in[1];
    const float* tgt_seq  = (const float*)d_in[2];
    const float* vec_h    = (const float*)d_in[3];
    const float* vec_c    = (const float*)d_in[4];
    const float* dec0     = (const float*)d_in[5];
    const float* emb_W    = (const float*)d_in[6];
    const float* emb_b    = (const float*)d_in[7];
    const float* pos_tab  = (const float*)d_in[8];
    const float* Wq       = (const float*)d_in[9];
    const float* Wk       = (const float*)d_in[10];
    const float* Wv       = (const float*)d_in[11];
    const float* Wo       = (const float*)d_in[12];
    const float* ln1_g    = (const float*)d_in[13];
    const float* ln1_b    = (const float*)d_in[14];
    const float* ffn_W1   = (const float*)d_in[15];
    const float* ffn_b1   = (const float*)d_in[16];
    const float* ffn_W2   = (const float*)d_in[17];
    const float* ffn_b2   = (const float*)d_in[18];
    const float* ln2_g    = (const float*)d_in[19];
    const float* ln2_b    = (const float*)d_in[20];
    const float* lstm_Wx  = (const float*)d_in[21];
    const float* lstm_Wh  = (const float*)d_in[22];
    const float* lstm_b   = (const float*)d_in[23];
    const float* out_W    = (const float*)d_in[24];
    const float* out_b    = (const float*)d_in[25];
    const int*   epoch    = (const int*)  d_in[26];

    // ---- workspace layout (total 41,209,856 floats = 164.8 MB) ----
    float* ws = (float*)d_ws;
    const long NX = (long)B_ * S_ * DM_;           // 6,553,600
    float* X      = ws;                            // enc / residual [0, NX)
    float* R      = X + NX;                        // 34,603,008-float region
    // encoder phase:
    float* Qb     = R;
    float* Kb     = Qb + NX;
    float* Vb     = Kb + NX;
    float* Ob     = Vb + NX;
    float* FFNH   = Ob + NX;                       // 8,388,608
    // decoder phase (aliases into R; encoder scratch dead):
    float* WEFF_t = R;                             // [0, 4,194,304)
    float* G2m    = R + 4194304;                   // 800x4096 (dead after ENCB gemm)
    float* WT_A   = R + 7471104;                   // 4096 x 1536
    float* WT_B   = R + 13762560;                  // 4096 x 1024 (WEFF^T only)
    float* ENCB   = R + 17956864;                  // 64*16 x 4096 (B-step enc@G2)
    float* Hall   = R + 22151168;                  // B*S x 1024
    float* T1     = WEFF_t;                        // 2,244,608 (after tr_cat B)
    float* XB     = R + 3375104;                   // 64*16 x 800 gather buffer
    float* TAIL   = R + 34603008;
    float* G3v    = TAIL;                          // 4096
    // h-ring (ring_slot): [R+30539776,+248*16K) ; [R+4259840,+196*16K) ;
    //                     [R+2244608,+69*16K). All scan-dead; each addr once.
    unsigned* BAR = (unsigned*)G2m;                // sync lines (zeroed post-ENCB)

    const int M = B_ * S_; // 8192
    dim3 blk(256);

    // ---- encoder ----
    gemm128<<<dim3(M / 128, (DM_ + 127) / 128), blk, 0, stream>>>(
        src_seq, emb_W, X, M, DM_, FRAME_, emb_b, nullptr, src_pos, pos_tab, 0);
    gemm128<<<dim3(M / 128, (DM_ + 127) / 128), blk, 0, stream>>>(
        X, Wq, Qb, M, DM_, DM_, nullptr, nullptr, nullptr, nullptr, 0);
    gemm128<<<dim3(M / 128, (DM_ + 127) / 128), blk, 0, stream>>>(
        X, Wk, Kb, M, DM_, DM_, nullptr, nullptr, nullptr, nullptr, 0);
    gemm128<<<dim3(M / 128, (DM_ + 127) / 128), blk, 0, stream>>>(
        X, Wv, Vb, M, DM_, DM_, nullptr, nullptr, nullptr, nullptr, 0);
    attn_f32<<<dim3(B_ * H_ * (S_ / 4)), blk, 0, stream>>>(Qb, Kb, Vb, Ob);
    gemm128<<<dim3(M / 128, (DM_ + 127) / 128), blk, 0, stream>>>(
        Ob, Wo, FFNH, M, DM_, DM_, nullptr, X, nullptr, nullptr, 0);
    ln_f32<<<dim3(M), blk, 0, stream>>>(FFNH, X, ln1_g, ln1_b, DM_);
    gemm128<<<dim3(M / 128, FFN_ / 128), blk, 0, stream>>>(
        X, ffn_W1, FFNH, M, FFN_, DM_, ffn_b1, nullptr, nullptr, nullptr, 1);
    gemm128<<<dim3(M / 128, (DM_ + 127) / 128), blk, 0, stream>>>(
        FFNH, ffn_W2, Ob, M, DM_, FFN_, ffn_b2, X, nullptr, nullptr, 0);
    ln_f32<<<dim3(M), blk, 0, stream>>>(Ob, X, ln2_g, ln2_b, DM_);   // X = enc

    // ---- decoder precompute ----
    gemm128<<<dim3(HID_ / 128, G4_ / 128), blk, 0, stream>>>(
        out_W, lstm_Wx, WEFF_t, HID_, G4_, POSE_, nullptr, lstm_Wh, nullptr, nullptr, 0);
    gemm128<<<dim3((DM_ + 127) / 128, G4_ / 128), blk, 0, stream>>>(
        out_W + (long)HID_ * POSE_, lstm_Wx, G2m, DM_, G4_, POSE_,
        nullptr, nullptr, nullptr, nullptr, 0);
    tr_cat<<<dim3(KPA_ / 64, G4_ / 64), blk, 0, stream>>>(
        lstm_Wh, lstm_Wx, WT_A, HID_, POSE_, KPA_);
    tr_cat<<<dim3(KPB_ / 64, G4_ / 64), blk, 0, stream>>>(
        WEFF_t, WEFF_t, WT_B, HID_, 0, KPB_);      // WEFF^T only
    xb_gather<<<dim3(NSLOT_ * 16 * 800 / 256), blk, 0, stream>>>(X, XB, epoch);
    g3_kernel<<<dim3(G4_ / 256), blk, 0, stream>>>(out_b, lstm_Wx, G3v);
    // ENCB = XB @ G2m  (reads G2m -> must precede init_state's BAR zeroing)
    gemm128<<<dim3(NSLOT_ * 16 / 128, G4_ / 128), blk, 0, stream>>>(
        XB, G2m, ENCB, NSLOT_ * 16, G4_, DM_, nullptr, nullptr, nullptr, nullptr, 0);
    init_state<<<dim3((B_ * HID_ + 255) / 256), blk, 0, stream>>>(
        vec_h, ring_slot(R, 0), BAR);
    gemm128<<<dim3(M / 128, (POSE_ + 127) / 128), blk, 0, stream>>>(
        X, out_W + (long)HID_ * POSE_, T1, M, POSE_, DM_, out_b,
        nullptr, nullptr, nullptr, 0);

    // ---- fused sequential scan: register-direct h, 3 syncs/step ----
    lstm_scan<<<dim3(NBLK_SCAN), blk, 0, stream>>>(
        R, vec_c, WT_A, WT_B, G3v, lstm_b, epoch,
        tgt_seq, dec0, ENCB, Hall, BAR);

    // ---- final: out = Hall@out_W[:1024] + T1 ----
    gemm128<<<dim3(M / 128, (POSE_ + 127) / 128), blk, 0, stream>>>(
        Hall, out_W, (float*)d_out, M, POSE_, HID_, nullptr, T1,
        nullptr, nullptr, 0);
}

// Round 11
// 8447.572 us; speedup vs baseline: 2.4332x; 1.0633x over previous
//
#include <hip/hip_runtime.h>
#include <math.h>

#define B_ 16
#define S_ 512
#define FRAME_ 438
#define DM_ 800
#define H_ 8
#define DH_ 100
#define FFN_ 1024
#define HID_ 1024
#define POSE_ 274
#define WIN_ 100
#define G4_ 4096     // 4*HID
#define KPA_ 1536    // padded K for WT_A ([Wh;Wx], K=1298)
#define KPB_ 1024    // K for WT_B (WEFF^T only; enc part precomputed in ENCB)
#define NBLK_SCAN 512
#define WLS_ 1312    // LDS row stride for WT_A slice (>=1298, mult of 4)
#define WLSZ_ (8 * WLS_ + 256)  // + zero tail (guards row-7 k>=1312 reads; h/tgt=0 there)
#define NSLOT_ 64    // ENCB slots (46 needed at epoch=100)

// h-ring: 513 slots x 16384 floats (64 KB), layout [b][hid] (natural).
// Slot n holds h after step n-1. Addresses used ONCE: written (sc0/sc1->MALL)
// at step n-1, read (normal cached, L2-absorbed broadcast) at step n.
#define RING_SLOT_F 16384L

// ---------------------------------------------------------------------------
// Coherent (MALL-point) helpers. sc0 sc1 = bypass L1/L2, serve at LLC.
// Lessons r2/r3: never bulk data through these. Lesson r6/r7: UC-poll spin
// time must be bounded to barrier skew -- ONE poll site per step, after all
// step work; polled lines written ONLY by st_coh (clean), never RMW'd.
// ---------------------------------------------------------------------------
__device__ __forceinline__ void st_coh(float* p, float v)
{
    asm volatile("global_store_dword %0, %1, off sc0 sc1"
                 :: "v"(p), "v"(v) : "memory");
}

__device__ __forceinline__ void st_coh_u32(unsigned* p, unsigned v)
{
    asm volatile("global_store_dword %0, %1, off sc0 sc1"
                 :: "v"(p), "v"(v) : "memory");
}

__device__ __forceinline__ unsigned ld_coh_u32(const unsigned* p)
{
    unsigned v;
    asm volatile("global_load_dword %0, %1, off sc0 sc1\n\t"
                 "s_waitcnt vmcnt(0)"
                 : "=v"(v) : "v"(p) : "memory");
    return v;
}

__host__ __device__ __forceinline__ float* ring_slot(float* R, int n)
{
    long off;
    if (n < 248)      off = 30539776L + (long)n * RING_SLOT_F;        // Hall..TAIL gap
    else if (n < 444) off = 4259840L + (long)(n - 248) * RING_SLOT_F; // dead G2 (past BAR)
    else              off = 2244608L + (long)(n - 444) * RING_SLOT_F; // dead WEFF_t tail
    return R + off;
}

// ---------------------------------------------------------------------------
// gemm128 v3: fp32, 128x128 tile, 256 thr, 8x8 micro, double-buffered LDS
// (r9/r10-verified) + guard-free fast path for interior tiles (same loaded
// values -> bitwise identical).
// ---------------------------------------------------------------------------
__global__ __launch_bounds__(256) void gemm128(
    const float* __restrict__ A, const float* __restrict__ Bm,
    float* __restrict__ C, int M, int N, int K,
    const float* __restrict__ bias, const float* __restrict__ res,
    const int* __restrict__ posidx, const float* __restrict__ postab,
    int relu)
{
    __shared__ float As[2][16 * 132];
    __shared__ float Bs[2][16 * 132];
    int m0 = blockIdx.x * 128, n0 = blockIdx.y * 128;
    int tid = threadIdx.x;
    int tx = tid & 15, ty = tid >> 4;
    float acc[8][8];
#pragma unroll
    for (int i = 0; i < 8; ++i)
#pragma unroll
        for (int j = 0; j < 8; ++j) acc[i][j] = 0.f;

    bool fullM = (m0 + 128 <= M);
    bool fullN = (n0 + 128 <= N);

    float ra[8], rb[8];
    auto loadA = [&](int k0) {
        bool fullK = (k0 + 16 <= K);
        if (fullM && fullK) {
#pragma unroll
            for (int i = 0; i < 8; ++i) {
                int idx = i * 256 + tid;
                ra[i] = A[(long)(m0 + (idx >> 4)) * K + k0 + (idx & 15)];
            }
        } else {
#pragma unroll
            for (int i = 0; i < 8; ++i) {
                int idx = i * 256 + tid;
                int r = m0 + (idx >> 4), k = k0 + (idx & 15);
                ra[i] = (r < M && k < K) ? A[(long)r * K + k] : 0.f;
            }
        }
    };
    auto loadB = [&](int k0) {
        bool fullK = (k0 + 16 <= K);
        if (fullN && fullK) {
#pragma unroll
            for (int i = 0; i < 8; ++i) {
                int idx = i * 256 + tid;
                rb[i] = Bm[(long)(k0 + (idx >> 7)) * N + n0 + (idx & 127)];
            }
        } else {
#pragma unroll
            for (int i = 0; i < 8; ++i) {
                int idx = i * 256 + tid;
                int kk = k0 + (idx >> 7), nn = n0 + (idx & 127);
                rb[i] = (kk < K && nn < N) ? Bm[(long)kk * N + nn] : 0.f;
            }
        }
    };

    loadA(0); loadB(0);
    int cur = 0;
    for (int k0 = 0; k0 < K; k0 += 16) {
#pragma unroll
        for (int i = 0; i < 8; ++i) {
            int idx = i * 256 + tid;
            As[cur][(idx & 15) * 132 + (idx >> 4)] = ra[i];
        }
#pragma unroll
        for (int i = 0; i < 8; ++i) {
            int idx = i * 256 + tid;
            Bs[cur][(idx >> 7) * 132 + (idx & 127)] = rb[i];
        }
        __syncthreads();
        if (k0 + 16 < K) { loadA(k0 + 16); loadB(k0 + 16); }  // overlap w/ compute
#pragma unroll
        for (int kk = 0; kk < 16; ++kk) {
            float4 a0 = *(const float4*)&As[cur][kk * 132 + ty * 4];
            float4 a1 = *(const float4*)&As[cur][kk * 132 + 64 + ty * 4];
            float4 b0 = *(const float4*)&Bs[cur][kk * 132 + tx * 4];
            float4 b1 = *(const float4*)&Bs[cur][kk * 132 + 64 + tx * 4];
            float a[8] = {a0.x, a0.y, a0.z, a0.w, a1.x, a1.y, a1.z, a1.w};
            float b[8] = {b0.x, b0.y, b0.z, b0.w, b1.x, b1.y, b1.z, b1.w};
#pragma unroll
            for (int i = 0; i < 8; ++i)
#pragma unroll
                for (int j = 0; j < 8; ++j) acc[i][j] += a[i] * b[j];
        }
        cur ^= 1;   // writes next iter go to the other buffer (no 2nd sync)
    }
#pragma unroll
    for (int i = 0; i < 8; ++i) {
        int m = m0 + ((i < 4) ? (ty * 4 + i) : (64 + ty * 4 + i - 4));
        if (m >= M) continue;
#pragma unroll
        for (int j = 0; j < 8; ++j) {
            int n = n0 + ((j < 4) ? (tx * 4 + j) : (64 + tx * 4 + j - 4));
            if (n >= N) continue;
            float v = acc[i][j];
            if (bias) v += bias[n];
            if (res) v += res[(long)m * N + n];
            if (posidx) v += postab[(long)posidx[m] * N + n];
            if (relu) v = fmaxf(v, 0.f);
            C[(long)m * N + n] = v;
        }
    }
}

// ---------------------------------------------------------------------------
// LayerNorm over last dim N (=800), one block per row.
// ---------------------------------------------------------------------------
__global__ __launch_bounds__(256) void ln_f32(
    const float* __restrict__ X, float* __restrict__ Y,
    const float* __restrict__ g, const float* __restrict__ b, int N)
{
    int m = blockIdx.x;
    const float* x = X + (long)m * N;
    __shared__ float red[256];
    int tid = threadIdx.x;
    float s = 0.f;
    for (int i = tid; i < N; i += 256) s += x[i];
    red[tid] = s; __syncthreads();
    for (int o = 128; o > 0; o >>= 1) { if (tid < o) red[tid] += red[tid + o]; __syncthreads(); }
    float mean = red[0] / N;
    __syncthreads();
    float v = 0.f;
    for (int i = tid; i < N; i += 256) { float d = x[i] - mean; v += d * d; }
    red[tid] = v; __syncthreads();
    for (int o = 128; o > 0; o >>= 1) { if (tid < o) red[tid] += red[tid + o]; __syncthreads(); }
    float rs = rsqrtf(red[0] / N + 1e-6f);
    for (int i = tid; i < N; i += 256)
        Y[(long)m * N + i] = (x[i] - mean) * rs * g[i] + b[i];
}

// ---------------------------------------------------------------------------
// Fused banded attention (verified round 1).
// ---------------------------------------------------------------------------
__global__ __launch_bounds__(256) void attn_f32(
    const float* __restrict__ Q, const float* __restrict__ K,
    const float* __restrict__ V, float* __restrict__ O)
{
    int blk = blockIdx.x;
    int qt = blk & 127; int bh = blk >> 7;
    int h = bh & 7; int b = bh >> 3;
    int q0 = qt * 4;
    int tid = threadIdx.x;

    __shared__ float qv[4][DH_];
    __shared__ float sc[4][208];
    __shared__ float red[256];
    __shared__ float inv_den[4];

    for (int i = tid; i < 4 * DH_; i += 256) {
        int qi = i / DH_, d = i - qi * DH_;
        qv[qi][d] = Q[(long)(b * S_ + q0 + qi) * DM_ + h * DH_ + d];
    }
    __syncthreads();

    int w = tid;
    int k = q0 - WIN_ + w;
    bool kvalid = (w < 204) && (k >= 0) && (k < S_);
    float dots[4] = {0.f, 0.f, 0.f, 0.f};
    if (kvalid) {
        const float* krow = K + (long)(b * S_ + k) * DM_ + h * DH_;
        for (int d = 0; d < DH_; ++d) {
            float kvv = krow[d];
#pragma unroll
            for (int qi = 0; qi < 4; ++qi) dots[qi] += qv[qi][d] * kvv;
        }
    }
#pragma unroll
    for (int qi = 0; qi < 4; ++qi) {
        int wq = w - qi;
        if (w < 204 && wq >= 0 && wq < 201)
            sc[qi][wq] = kvalid ? dots[qi] * 0.1f : -1e30f;
    }
    __syncthreads();

    for (int qi = 0; qi < 4; ++qi) {
        float vmax = (tid < 201) ? sc[qi][tid] : -1e30f;
        red[tid] = vmax; __syncthreads();
        for (int o = 128; o > 0; o >>= 1) { if (tid < o) red[tid] = fmaxf(red[tid], red[tid + o]); __syncthreads(); }
        float mx = red[0];
        __syncthreads();
        float e = 0.f;
        if (tid < 201) { e = __expf(sc[qi][tid] - mx); sc[qi][tid] = e; }
        red[tid] = e; __syncthreads();
        for (int o = 128; o > 0; o >>= 1) { if (tid < o) red[tid] += red[tid + o]; __syncthreads(); }
        if (tid == 0) inv_den[qi] = 1.f / red[0];
        __syncthreads();
    }

    if (tid < DH_) {
        int d = tid;
        float o_[4] = {0.f, 0.f, 0.f, 0.f};
        for (int w2 = 0; w2 < 204; ++w2) {
            int k2 = q0 - WIN_ + w2;
            if (k2 < 0 || k2 >= S_) continue;
            float vv = V[(long)(b * S_ + k2) * DM_ + h * DH_ + d];
#pragma unroll
            for (int qi = 0; qi < 4; ++qi) {
                int wq = w2 - qi;
                if (wq >= 0 && wq < 201) o_[qi] += sc[qi][wq] * vv;
            }
        }
#pragma unroll
        for (int qi = 0; qi < 4; ++qi)
            O[(long)(b * S_ + q0 + qi) * DM_ + h * DH_ + d] = o_[qi] * inv_den[qi];
    }
}

// g3[j] = out_b @ Wx
__global__ __launch_bounds__(256) void g3_kernel(
    const float* __restrict__ outb, const float* __restrict__ Wx, float* __restrict__ g3)
{
    int j = blockIdx.x * 256 + threadIdx.x;
    if (j >= G4_) return;
    float s = 0.f;
    for (int p = 0; p < POSE_; ++p) s += outb[p] * Wx[(long)p * G4_ + j];
    g3[j] = s;
}

// init h state into ring slot 0 ([b][hid] natural layout) + zero sync state
__global__ __launch_bounds__(256) void init_state(
    const float* __restrict__ vh, float* __restrict__ ring0,
    unsigned* __restrict__ bar)
{
    int i = blockIdx.x * 256 + threadIdx.x;
    if (i < B_ * HID_) ring0[i] = vh[i];
    if (i < 4096) bar[i] = 0u;
}

// ---------------------------------------------------------------------------
// xb_gather: pack ENC rows needed by B-steps into XB[s*16+b][800].
// ---------------------------------------------------------------------------
__global__ __launch_bounds__(256) void xb_gather(
    const float* __restrict__ X, float* __restrict__ XB,
    const int* __restrict__ epoch)
{
    long idx = (long)blockIdx.x * 256 + threadIdx.x;   // < NSLOT_*16*800
    int s = (int)(idx / 12800);
    int rem = (int)(idx - (long)s * 12800);
    int bb = rem / 800, k = rem - bb * 800;
    int p = (int)((double)epoch[0] * 0.01);
    float v = 0.f;
    if (p > 0) {
        int per = p + 10;
        int t = (s / p) * per + (s % p);
        if (t >= 1 && t < S_) v = X[((long)bb * S_ + (t - 1)) * DM_ + k];
    }
    XB[idx] = v;
}

// ---------------------------------------------------------------------------
// tr_cat: WT[c][k] = (k<K1 ? in1[k][c] : k<K1+K2 ? in2[k-K1][c] : 0)
// ---------------------------------------------------------------------------
__global__ __launch_bounds__(256) void tr_cat(
    const float* __restrict__ in1, const float* __restrict__ in2,
    float* __restrict__ WT, int K1, int K2, int KP)
{
    __shared__ float tile[64][65];
    int k0 = blockIdx.x * 64, c0 = blockIdx.y * 64;
    int tid = threadIdx.x;
    int cl = tid & 63, kr = tid >> 6;
#pragma unroll
    for (int i = 0; i < 16; ++i) {
        int kl = i * 4 + kr;
        int k = k0 + kl, c = c0 + cl;
        float v = 0.f;
        if (k < K1) v = in1[(long)k * G4_ + c];
        else if (k < K1 + K2) v = in2[(long)(k - K1) * G4_ + c];
        tile[kl][cl] = v;
    }
    __syncthreads();
    int kl2 = tid & 63, cr = tid >> 6;
#pragma unroll
    for (int i = 0; i < 16; ++i) {
        int ci = i * 4 + cr;
        WT[(long)(c0 + ci) * KP + k0 + kl2] = tile[kl2][ci];
    }
}

// ---------------------------------------------------------------------------
// lstm_scan v10 = r10's verified register-direct structure +
//  - red reduce in [output][17] layout: reader's 16 partials are consecutive
//    (17 odd -> bijective mod 32 -> 2-way banks = free); writer 4-way. Same
//    q-ascending sum order -> bitwise identical.
//  - Hall store moved after the arrive so tid0's vmcnt(0) covers only the
//    2 h st_coh lines.
// Sync: r5/r8/r9/r10-proven chain (16-wide group RMW -> root RMW -> 32 clean
// gen replicas; ONE poll/step at first h use).
// LDS: WL 42 KB + red 8.5 KB + gst 0.5 KB = 51.2 KB.
// ---------------------------------------------------------------------------
__global__ __launch_bounds__(256, 2) void lstm_scan(
    float* __restrict__ Rbase,
    const float* __restrict__ vec_c,
    const float* __restrict__ WT_A, const float* __restrict__ WT_Bh,
    const float* __restrict__ g3, const float* __restrict__ lstm_b,
    const int* __restrict__ epoch,
    const float* __restrict__ tgt, const float* __restrict__ dec0,
    const float* __restrict__ ENCB, float* __restrict__ Hall,
    unsigned* __restrict__ bar)
{
    __shared__ float WL[WLSZ_];       // 8 WT_A rows, stride WLS_
    __shared__ float red[128 * 17];   // [output][17] (16 partials + pad)
    __shared__ float gst[128];

    int tid = threadIdx.x;
    int hid0 = blockIdx.x * 2;
    int kq = tid >> 4, b = tid & 15;
    int b3 = tid >> 1, hh = tid & 1;
    int p = (int)((double)epoch[0] * 0.01);   // match python int(epoch*LAMB)
    int per = p + 10;
    unsigned grp = (unsigned)blockIdx.x >> 4;  // 32 groups x 16 blocks
    unsigned* gcnt = bar;                      // 32 RMW lines (never polled)
    unsigned* root = bar + 1024;               // 1 RMW line  (never polled)
    unsigned* genA = bar + 1056;               // 32 clean replicas (st_coh only)

    // ---- one-time: stage this block's 8 WT_A rows into LDS ----
#pragma unroll
    for (int c = 0; c < 8; ++c) {
        const float* src = WT_A + (long)((c >> 1) * 1024 + hid0 + (c & 1)) * KPA_;
        for (int i = tid * 4; i < WLS_; i += 1024)
            *(float4*)&WL[c * WLS_ + i] = *(const float4*)&src[i];
    }
    for (int i = 8 * WLS_ + tid; i < WLSZ_; i += 256) WL[i] = 0.f;  // NaN guard

    float c_reg = 0.f;
    if (tid < 32) c_reg = vec_c[b3 * HID_ + hid0 + hh];
    __syncthreads();

    for (int t = 0; t < S_; ++t) {
        bool msk = (t % per) >= p;
        bool useA = msk || (t == 0);
        const float* hrd = ring_slot(Rbase, t);       // [b][hid]
        float*       hwr = ring_slot(Rbase, t + 1);

        float acc[8]  = {0.f, 0.f, 0.f, 0.f, 0.f, 0.f, 0.f, 0.f};
        float acc2[8] = {0.f, 0.f, 0.f, 0.f, 0.f, 0.f, 0.f, 0.f};

        // ---- 1. pre-wait: tgt/dec0 -> regs -> acc2 (no h, no LDS writes) ----
        if (useA) {
            const float* src = msk ? &tgt[((long)b * S_ + t) * POSE_]
                                   : &dec0[(long)b * POSE_];
            float4 tr4[4];
            float  tv[16];
#pragma unroll
            for (int j4 = 0; j4 < 4; ++j4)
                tr4[j4] = *(const float4*)(src + kq * 16 + j4 * 4);  // k' <= 255
#pragma unroll
            for (int j = 0; j < 16; ++j) {
                int kk = 256 + kq * 16 + j;
                tv[j] = (kk < POSE_) ? src[kk] : 0.f;   // zero beyond 274 (pan semantics)
            }
            // phase 1024 (j4 asc), then phase 1280 (j4 asc) -- r9/r10 order
#pragma unroll
            for (int j4 = 0; j4 < 4; ++j4) {
                float4 w[8];
#pragma unroll
                for (int c = 0; c < 8; ++c)
                    w[c] = *(const float4*)&WL[c * WLS_ + 1024 + kq * 16 + j4 * 4];
                float4 h4 = tr4[j4];
#pragma unroll
                for (int c = 0; c < 8; ++c)
                    acc2[c] += w[c].x * h4.x + w[c].y * h4.y + w[c].z * h4.z + w[c].w * h4.w;
            }
#pragma unroll
            for (int j4 = 0; j4 < 4; ++j4) {
                float4 w[8];
#pragma unroll
                for (int c = 0; c < 8; ++c)
                    w[c] = *(const float4*)&WL[c * WLS_ + 1280 + kq * 16 + j4 * 4];
#pragma unroll
                for (int c = 0; c < 8; ++c)
                    acc2[c] += w[c].x * tv[j4 * 4 + 0] + w[c].y * tv[j4 * 4 + 1]
                             + w[c].z * tv[j4 * 4 + 2] + w[c].w * tv[j4 * 4 + 3];
            }
        }

        // ---- 2. WAIT for h_t (one poll site/step; clean replica line) ----
        if (t > 0) {
            if (tid == 0)
                while (ld_coh_u32(&genA[grp * 32]) < (unsigned)t)
                    __builtin_amdgcn_s_sleep(2);
            __syncthreads();   // S1 (also orders prev step's red/gst hazards)
        }

        // ---- 3. h -> regs (16 float4, one batch; L2-absorbed broadcast) ----
        float4 hr[16];
        {
            const float* hb = hrd + (long)b * HID_;
#pragma unroll
            for (int ph = 0; ph < 4; ++ph) {
                const float* q = hb + ph * 256 + kq * 16;
                hr[ph * 4 + 0] = *(const float4*)(q);
                hr[ph * 4 + 1] = *(const float4*)(q + 4);
                hr[ph * 4 + 2] = *(const float4*)(q + 8);
                hr[ph * 4 + 3] = *(const float4*)(q + 12);
            }
        }
        if (useA) {
#pragma unroll
            for (int ph = 0; ph < 4; ++ph) {
                int kb = ph * 256 + kq * 16;
#pragma unroll
                for (int j4 = 0; j4 < 4; ++j4) {
                    float4 w[8];
#pragma unroll
                    for (int c = 0; c < 8; ++c)
                        w[c] = *(const float4*)&WL[c * WLS_ + kb + j4 * 4];
                    float4 h4 = hr[ph * 4 + j4];
#pragma unroll
                    for (int c = 0; c < 8; ++c)
                        acc[c] += w[c].x * h4.x + w[c].y * h4.y + w[c].z * h4.z + w[c].w * h4.w;
                }
            }
        } else {
            const float* wrow[8];
#pragma unroll
            for (int c = 0; c < 8; ++c)
                wrow[c] = WT_Bh + (long)((c >> 1) * 1024 + hid0 + (c & 1)) * KPB_;
#pragma unroll
            for (int ph = 0; ph < 4; ++ph) {
                int kb = ph * 256 + kq * 16;
#pragma unroll
                for (int j4 = 0; j4 < 4; ++j4) {
                    float4 w[8];
#pragma unroll
                    for (int c = 0; c < 8; ++c)
                        w[c] = *(const float4*)(wrow[c] + kb + j4 * 4);
                    float4 h4 = hr[ph * 4 + j4];
#pragma unroll
                    for (int c = 0; c < 8; ++c)
                        acc[c] += w[c].x * h4.x + w[c].y * h4.y + w[c].z * h4.z + w[c].w * h4.w;
                }
            }
        }

        // ---- 4. reduce 16 k-slices: red[(b*8+c)*17 + kq] ----
#pragma unroll
        for (int c = 0; c < 8; ++c)
            red[(b * 8 + c) * 17 + kq] = acc[c] + acc2[c];
        __syncthreads();   // S2

        if (tid < 128) {
            int ob = tid >> 3, oc = tid & 7;
            const float* rr = &red[tid * 17];      // 16 consecutive partials
            float s = 0.f;
#pragma unroll
            for (int q = 0; q < 16; ++q) s += rr[q];
            int gcol = (oc >> 1) * 1024 + hid0 + (oc & 1);
            s += lstm_b[gcol];
            if (!useA) {
                int sidx = ((t / per) * p + (t % per)) & (NSLOT_ - 1);
                s += g3[gcol] + ENCB[((long)(sidx * 16 + ob)) * G4_ + gcol];
            }
            gst[oc * 16 + ob] = s;
        }
        __syncthreads();   // S3

        float hn = 0.f;
        if (tid < 32) {
            int hid = hid0 + hh;
            float iv = gst[(0 * 2 + hh) * 16 + b3];
            float fv = gst[(1 * 2 + hh) * 16 + b3];
            float gv = gst[(2 * 2 + hh) * 16 + b3];
            float ov = gst[(3 * 2 + hh) * 16 + b3];
            float ig = 1.f / (1.f + __expf(-iv));
            float fg = 1.f / (1.f + __expf(-fv));
            float og = 1.f / (1.f + __expf(-ov));
            float cn = fg * c_reg + ig * tanhf(gv);
            hn = og * tanhf(cn);
            c_reg = cn;
            st_coh(&hwr[(long)b3 * HID_ + hid], hn);       // write-through to MALL
        }

        // ---- 5. ARRIVE (proven chain; wave 0, vmcnt covers h st_coh only) ----
        if (tid == 0) {
            asm volatile("s_waitcnt vmcnt(0)" ::: "memory");
            unsigned tk = __hip_atomic_fetch_add(&gcnt[grp * 32], 1u,
                              __ATOMIC_RELAXED, __HIP_MEMORY_SCOPE_AGENT);
            if (tk == (unsigned)(16 * t + 15)) {            // last in group
                unsigned r = __hip_atomic_fetch_add(root, 1u,
                                 __ATOMIC_RELAXED, __HIP_MEMORY_SCOPE_AGENT);
                if (r == (unsigned)(32 * t + 31)) {         // last group
#pragma unroll
                    for (int j = 0; j < 32; ++j)
                        st_coh_u32(&genA[j * 32], (unsigned)(t + 1));
                }
            }
        }
        // Hall store off the arrive's vmcnt path (read only post-kernel)
        if (tid < 32)
            Hall[((long)b3 * S_ + t) * HID_ + (hid0 + hh)] = hn;
        // no trailing sync needed: next step's pre-wait section touches no LDS;
        // red/gst WAR hazards are ordered by next step's S1 (wait) barrier.
    }
}

// ---------------------------------------------------------------------------
extern "C" void kernel_launch(void* const* d_in, const int* in_sizes, int n_in,
                              void* d_out, int out_size, void* d_ws, size_t ws_size,
                              hipStream_t stream) {
    const float* src_seq  = (const float*)d_in[0];
    const int*   src_pos  = (const int*)  d_in[1];
    const float* tgt_seq  = (const float*)d_in[2];
    const float* vec_h    = (const float*)d_in[3];
    const float* vec_c    = (const float*)d_in[4];
    const float* dec0     = (const float*)d_in[5];
    const float* emb_W    = (const float*)d_in[6];
    const float* emb_b    = (const float*)d_in[7];
    const float* pos_tab  = (const float*)d_in[8];
    const float* Wq       = (const float*)d_in[9];
    const float* Wk       = (const float*)d_in[10];
    const float* Wv       = (const float*)d_in[11];
    const float* Wo       = (const float*)d_in[12];
    const float* ln1_g    = (const float*)d_in[13];
    const float* ln1_b    = (const float*)d_in[14];
    const float* ffn_W1   = (const float*)d_in[15];
    const float* ffn_b1   = (const float*)d_in[16];
    const float* ffn_W2   = (const float*)d_in[17];
    const float* ffn_b2   = (const float*)d_in[18];
    const float* ln2_g    = (const float*)d_in[19];
    const float* ln2_b    = (const float*)d_in[20];
    const float* lstm_Wx  = (const float*)d_in[21];
    const float* lstm_Wh  = (const float*)d_in[22];
    const float* lstm_b   = (const float*)d_in[23];
    const float* out_W    = (const float*)d_in[24];
    const float* out_b    = (const float*)d_in[25];
    const int*   epoch    = (const int*)  d_in[26];

    // ---- workspace layout (total 41,209,856 floats = 164.8 MB) ----
    float* ws = (float*)d_ws;
    const long NX = (long)B_ * S_ * DM_;           // 6,553,600
    float* X      = ws;                            // enc / residual [0, NX)
    float* R      = X + NX;                        // 34,603,008-float region
    // encoder phase:
    float* Qb     = R;
    float* Kb     = Qb + NX;
    float* Vb     = Kb + NX;
    float* Ob     = Vb + NX;
    float* FFNH   = Ob + NX;                       // 8,388,608
    // decoder phase (aliases into R; encoder scratch dead):
    float* WEFF_t = R;                             // [0, 4,194,304)
    float* G2m    = R + 4194304;                   // 800x4096 (dead after ENCB gemm)
    float* WT_A   = R + 7471104;                   // 4096 x 1536
    float* WT_B   = R + 13762560;                  // 4096 x 1024 (WEFF^T only)
    float* ENCB   = R + 17956864;                  // 64*16 x 4096 (B-step enc@G2)
    float* Hall   = R + 22151168;                  // B*S x 1024
    float* T1     = WEFF_t;                        // 2,244,608 (after tr_cat B)
    float* XB     = R + 3375104;                   // 64*16 x 800 gather buffer
    float* TAIL   = R + 34603008;
    float* G3v    = TAIL;                          // 4096
    // h-ring (ring_slot): [R+30539776,+248*16K) ; [R+4259840,+196*16K) ;
    //                     [R+2244608,+69*16K). All scan-dead; each addr once.
    unsigned* BAR = (unsigned*)G2m;                // sync lines (zeroed post-ENCB)

    const int M = B_ * S_; // 8192
    dim3 blk(256);

    // ---- encoder ----
    gemm128<<<dim3(M / 128, (DM_ + 127) / 128), blk, 0, stream>>>(
        src_seq, emb_W, X, M, DM_, FRAME_, emb_b, nullptr, src_pos, pos_tab, 0);
    gemm128<<<dim3(M / 128, (DM_ + 127) / 128), blk, 0, stream>>>(
        X, Wq, Qb, M, DM_, DM_, nullptr, nullptr, nullptr, nullptr, 0);
    gemm128<<<dim3(M / 128, (DM_ + 127) / 128), blk, 0, stream>>>(
        X, Wk, Kb, M, DM_, DM_, nullptr, nullptr, nullptr, nullptr, 0);
    gemm128<<<dim3(M / 128, (DM_ + 127) / 128), blk, 0, stream>>>(
        X, Wv, Vb, M, DM_, DM_, nullptr, nullptr, nullptr, nullptr, 0);
    attn_f32<<<dim3(B_ * H_ * (S_ / 4)), blk, 0, stream>>>(Qb, Kb, Vb, Ob);
    gemm128<<<dim3(M / 128, (DM_ + 127) / 128), blk, 0, stream>>>(
        Ob, Wo, FFNH, M, DM_, DM_, nullptr, X, nullptr, nullptr, 0);
    ln_f32<<<dim3(M), blk, 0, stream>>>(FFNH, X, ln1_g, ln1_b, DM_);
    gemm128<<<dim3(M / 128, FFN_ / 128), blk, 0, stream>>>(
        X, ffn_W1, FFNH, M, FFN_, DM_, ffn_b1, nullptr, nullptr, nullptr, 1);
    gemm128<<<dim3(M / 128, (DM_ + 127) / 128), blk, 0, stream>>>(
        FFNH, ffn_W2, Ob, M, DM_, FFN_, ffn_b2, X, nullptr, nullptr, 0);
    ln_f32<<<dim3(M), blk, 0, stream>>>(Ob, X, ln2_g, ln2_b, DM_);   // X = enc

    // ---- decoder precompute ----
    gemm128<<<dim3(HID_ / 128, G4_ / 128), blk, 0, stream>>>(
        out_W, lstm_Wx, WEFF_t, HID_, G4_, POSE_, nullptr, lstm_Wh, nullptr, nullptr, 0);
    gemm128<<<dim3((DM_ + 127) / 128, G4_ / 128), blk, 0, stream>>>(
        out_W + (long)HID_ * POSE_, lstm_Wx, G2m, DM_, G4_, POSE_,
        nullptr, nullptr, nullptr, nullptr, 0);
    tr_cat<<<dim3(KPA_ / 64, G4_ / 64), blk, 0, stream>>>(
        lstm_Wh, lstm_Wx, WT_A, HID_, POSE_, KPA_);
    tr_cat<<<dim3(KPB_ / 64, G4_ / 64), blk, 0, stream>>>(
        WEFF_t, WEFF_t, WT_B, HID_, 0, KPB_);      // WEFF^T only
    xb_gather<<<dim3(NSLOT_ * 16 * 800 / 256), blk, 0, stream>>>(X, XB, epoch);
    g3_kernel<<<dim3(G4_ / 256), blk, 0, stream>>>(out_b, lstm_Wx, G3v);
    // ENCB = XB @ G2m  (reads G2m -> must precede init_state's BAR zeroing)
    gemm128<<<dim3(NSLOT_ * 16 / 128, G4_ / 128), blk, 0, stream>>>(
        XB, G2m, ENCB, NSLOT_ * 16, G4_, DM_, nullptr, nullptr, nullptr, nullptr, 0);
    init_state<<<dim3((B_ * HID_ + 255) / 256), blk, 0, stream>>>(
        vec_h, ring_slot(R, 0), BAR);
    gemm128<<<dim3(M / 128, (POSE_ + 127) / 128), blk, 0, stream>>>(
        X, out_W + (long)HID_ * POSE_, T1, M, POSE_, DM_, out_b,
        nullptr, nullptr, nullptr, 0);

    // ---- fused sequential scan: register-direct h, conflict-free reduce ----
    lstm_scan<<<dim3(NBLK_SCAN), blk, 0, stream>>>(
        R, vec_c, WT_A, WT_B, G3v, lstm_b, epoch,
        tgt_seq, dec0, ENCB, Hall, BAR);

    // ---- final: out = Hall@out_W[:1024] + T1 ----
    gemm128<<<dim3(M / 128, (POSE_ + 127) / 128), blk, 0, stream>>>(
        Hall, out_W, (float*)d_out, M, POSE_, HID_, nullptr, T1,
        nullptr, nullptr, 0);
}